// Round 1
// baseline (413.483 us; speedup 1.0000x reference)
//
#include <hip/hip_runtime.h>

typedef _Float16 half_t;
typedef _Float16 f16x8 __attribute__((ext_vector_type(8)));
typedef _Float16 f16x4 __attribute__((ext_vector_type(4)));
typedef float f32x4 __attribute__((ext_vector_type(4)));

#define D_MODEL 1024
#define BS 4
#define SEQ 4096
#define ROWS (BS * SEQ)   // 16384
#define SC 128
#define NC (SEQ / SC)     // 32

__device__ __forceinline__ void gld_lds16(const void* g, void* l) {
  __builtin_amdgcn_global_load_lds((const __attribute__((address_space(1))) void*)g,
                                   (__attribute__((address_space(3))) void*)l, 16, 0, 0);
}

// ---------------- LayerNorm: fp32 in -> f16 out ----------------
__global__ __launch_bounds__(256) void ln_kernel(const float* __restrict__ x,
                                                 const float* __restrict__ gamma,
                                                 const float* __restrict__ beta,
                                                 half_t* __restrict__ h) {
  const int row = blockIdx.x;
  const int t = threadIdx.x;
  const float* xr = x + (size_t)row * D_MODEL + t * 4;
  f32x4 v = *(const f32x4*)xr;
  float s = v[0] + v[1] + v[2] + v[3];
  float q = v[0]*v[0] + v[1]*v[1] + v[2]*v[2] + v[3]*v[3];
#pragma unroll
  for (int off = 32; off > 0; off >>= 1) {
    s += __shfl_down(s, off, 64);
    q += __shfl_down(q, off, 64);
  }
  __shared__ float rs[4], rq[4];
  const int wv = t >> 6, ln = t & 63;
  if (ln == 0) { rs[wv] = s; rq[wv] = q; }
  __syncthreads();
  s = rs[0] + rs[1] + rs[2] + rs[3];
  q = rq[0] + rq[1] + rq[2] + rq[3];
  const float mu = s * (1.0f / D_MODEL);
  const float var = q * (1.0f / D_MODEL) - mu * mu;
  const float rstd = rsqrtf(var + 1e-5f);
  f32x4 g = *(const f32x4*)(gamma + t * 4);
  f32x4 b = *(const f32x4*)(beta + t * 4);
  f16x4 o;
#pragma unroll
  for (int i = 0; i < 4; i++) o[i] = (half_t)((v[i] - mu) * rstd * g[i] + b[i]);
  *(f16x4*)(h + (size_t)row * D_MODEL + t * 4) = o;
}

// ---------------- weight prepack: fp32 [K][N] -> f16 [N][K] ----------------
__global__ __launch_bounds__(256) void prep_w(const float* __restrict__ Wq,
                                              const float* __restrict__ Wk,
                                              const float* __restrict__ Wv,
                                              const float* __restrict__ Wqa,
                                              const float* __restrict__ Wka,
                                              half_t* __restrict__ wcat,
                                              half_t* __restrict__ wqa,
                                              half_t* __restrict__ wka) {
  const int b = blockIdx.x;
  const int mat = b >> 10;       // 5 matrices x 1024 tiles
  const int tile = b & 1023;
  const int tn = (tile & 31) * 32;
  const int tk = (tile >> 5) * 32;
  const float* W = mat == 0 ? Wq : mat == 1 ? Wk : mat == 2 ? Wv : mat == 3 ? Wqa : Wka;
  half_t* dst = mat < 3 ? wcat + (size_t)mat * D_MODEL * D_MODEL : (mat == 3 ? wqa : wka);
  __shared__ float tl[32][33];
  const int tx = threadIdx.x & 31, ty = threadIdx.x >> 5;
#pragma unroll
  for (int i = 0; i < 32; i += 8)
    tl[ty + i][tx] = W[(size_t)(tk + ty + i) * D_MODEL + tn + tx];
  __syncthreads();
#pragma unroll
  for (int i = 0; i < 32; i += 8)
    dst[(size_t)(tn + ty + i) * D_MODEL + tk + tx] = (half_t)tl[tx][ty + i];
}

__global__ __launch_bounds__(256) void copy_bias(const float* __restrict__ bq,
                                                 const float* __restrict__ bk,
                                                 const float* __restrict__ bv,
                                                 float* __restrict__ bcat) {
  const int i = blockIdx.x * 256 + threadIdx.x;
  if (i < 1024) bcat[i] = bq[i];
  else if (i < 2048) bcat[i] = bk[i - 1024];
  else if (i < 3072) bcat[i] = bv[i - 2048];
}

// ---------------- f16 MFMA GEMM: C[M][N] = A[M][K] @ Bt[N][K]^T + bias ----------------
// 128x128 tile, BK=32, 4 waves each 64x64, 16x16x32 f16 MFMA, global_load_lds staging.
__global__ __launch_bounds__(256) void gemm_f16(const half_t* __restrict__ A, int lda,
                                                const half_t* __restrict__ Bt,
                                                const float* __restrict__ bias,
                                                half_t* __restrict__ C, int ldc,
                                                int K) {
  __shared__ half_t As[128][32];
  __shared__ half_t Bsh[128][32];
  const int n0 = blockIdx.x * 128;
  const int m0 = blockIdx.y * 128;
  const int t = threadIdx.x;
  const int wv = t >> 6, ln = t & 63;
  const int wr = wv >> 1, wc = wv & 1;

  // staging: lane -> (row = ln>>2, kcol = (ln&3)*8); LDS dest linear = lane*16B
  const int srow = ln >> 2;
  const int skol = (ln & 3) * 8;
  const half_t* Ag = A + (size_t)(m0 + wv * 32 + srow) * lda + skol;
  const half_t* Bg = Bt + (size_t)(n0 + wv * 32 + srow) * K + skol;
  half_t* lA0 = &As[wv * 32][0];
  half_t* lA1 = &As[wv * 32 + 16][0];
  half_t* lB0 = &Bsh[wv * 32][0];
  half_t* lB1 = &Bsh[wv * 32 + 16][0];

  const int fr = ln & 15;          // fragment row/col
  const int fk = (ln >> 4) * 8;    // fragment k offset

  f32x4 acc[4][4] = {};

  for (int kt = 0; kt < K; kt += 32) {
    __syncthreads();
    gld_lds16(Ag + kt, lA0);
    gld_lds16(Ag + kt + (size_t)16 * lda, lA1);
    gld_lds16(Bg + kt, lB0);
    gld_lds16(Bg + kt + (size_t)16 * K, lB1);
    __syncthreads();
    f16x8 af[4], bf[4];
#pragma unroll
    for (int m = 0; m < 4; m++) af[m] = *(const f16x8*)&As[wr * 64 + m * 16 + fr][fk];
#pragma unroll
    for (int n = 0; n < 4; n++) bf[n] = *(const f16x8*)&Bsh[wc * 64 + n * 16 + fr][fk];
#pragma unroll
    for (int m = 0; m < 4; m++)
#pragma unroll
      for (int n = 0; n < 4; n++)
        acc[m][n] = __builtin_amdgcn_mfma_f32_16x16x32_f16(af[m], bf[n], acc[m][n], 0, 0, 0);
  }

  const int r0 = m0 + wr * 64 + (ln >> 4) * 4;
  const int c0 = n0 + wc * 64 + (ln & 15);
#pragma unroll
  for (int m = 0; m < 4; m++) {
#pragma unroll
    for (int n = 0; n < 4; n++) {
      const int col = c0 + n * 16;
      const float bb = bias[col];
#pragma unroll
      for (int r = 0; r < 4; r++) {
        const int row = r0 + m * 16 + r;
        C[(size_t)row * ldc + col] = (half_t)(acc[m][n][r] + bb);
      }
    }
  }
}

// ---------------- row softmax over D=1024 (in-place capable), logits scaled 1/32 ----------------
__global__ __launch_bounds__(256) void softmax_k(const half_t* __restrict__ L,
                                                 half_t* __restrict__ O) {
  const size_t row = blockIdx.x;
  const int t = threadIdx.x;
  f16x4 v = *(const f16x4*)(L + row * D_MODEL + t * 4);
  float x[4];
#pragma unroll
  for (int i = 0; i < 4; i++) x[i] = (float)v[i] * 0.03125f;  // 1/sqrt(1024)
  float mx = fmaxf(fmaxf(x[0], x[1]), fmaxf(x[2], x[3]));
#pragma unroll
  for (int off = 32; off > 0; off >>= 1) mx = fmaxf(mx, __shfl_xor(mx, off, 64));
  __shared__ float sm[4], ssum[4];
  const int wv = t >> 6, ln = t & 63;
  if (ln == 0) sm[wv] = mx;
  __syncthreads();
  mx = fmaxf(fmaxf(sm[0], sm[1]), fmaxf(sm[2], sm[3]));
  float e[4]; float s = 0.f;
#pragma unroll
  for (int i = 0; i < 4; i++) { e[i] = expf(x[i] - mx); s += e[i]; }
#pragma unroll
  for (int off = 32; off > 0; off >>= 1) s += __shfl_xor(s, off, 64);
  if (ln == 0) ssum[wv] = s;
  __syncthreads();
  s = ssum[0] + ssum[1] + ssum[2] + ssum[3];
  const float r = 1.0f / s;
  f16x4 o;
#pragma unroll
  for (int i = 0; i < 4; i++) o[i] = (half_t)(e[i] * r);
  *(f16x4*)(O + row * D_MODEL + t * 4) = o;
}

// ---------------- cumsum pass 1: per-chunk partial sums of A.*B ----------------
__global__ __launch_bounds__(256) void cs_partial(const half_t* __restrict__ A, int ldA,
                                                  const half_t* __restrict__ B, int ldB,
                                                  float* __restrict__ part) {
  const int d = blockIdx.x * 256 + threadIdx.x;
  const int c = blockIdx.y;
  const int bb = blockIdx.z;
  const size_t s0 = (size_t)bb * SEQ + (size_t)c * SC;
  const half_t* pa = A + s0 * ldA + d;
  const half_t* pb = B + s0 * ldB + d;
  float acc = 0.f;
#pragma unroll 8
  for (int s = 0; s < SC; s++) acc += (float)pa[(size_t)s * ldA] * (float)pb[(size_t)s * ldB];
  part[((size_t)bb * NC + c) * D_MODEL + d] = acc;
}

// ---------------- cumsum pass 2: prefix of partials + serial in-chunk scan,
//                  out = (cumsum(A.*B)/count) .* Cm  (f16 or f32 out) ----------------
template <bool HALF_OUT>
__global__ __launch_bounds__(256) void cs_apply(const half_t* __restrict__ A, int ldA,
                                                const half_t* __restrict__ B, int ldB,
                                                const half_t* __restrict__ Cm, int ldC,
                                                const float* __restrict__ part,
                                                half_t* __restrict__ OH,
                                                float* __restrict__ OF) {
  const int d = blockIdx.x * 256 + threadIdx.x;
  const int c = blockIdx.y;
  const int bb = blockIdx.z;
  float acc = 0.f;
  for (int cc = 0; cc < c; cc++) acc += part[((size_t)bb * NC + cc) * D_MODEL + d];
  const size_t s0 = (size_t)bb * SEQ + (size_t)c * SC;
#pragma unroll 4
  for (int s = 0; s < SC; s++) {
    const size_t sg = s0 + s;
    acc += (float)A[sg * ldA + d] * (float)B[sg * ldB + d];
    const float pooled = acc / (float)(c * SC + s + 1);
    const float m = pooled * (float)Cm[sg * ldC + d];
    if (HALF_OUT) OH[sg * D_MODEL + d] = (half_t)m;
    else          OF[sg * D_MODEL + d] = m;
  }
}

extern "C" void kernel_launch(void* const* d_in, const int* in_sizes, int n_in,
                              void* d_out, int out_size, void* d_ws, size_t ws_size,
                              hipStream_t stream) {
  const float* x     = (const float*)d_in[0];
  const float* Wq    = (const float*)d_in[2];
  const float* bq    = (const float*)d_in[3];
  const float* Wqa   = (const float*)d_in[4];
  const float* bqa   = (const float*)d_in[5];
  const float* Wk    = (const float*)d_in[6];
  const float* bk    = (const float*)d_in[7];
  const float* Wka   = (const float*)d_in[8];
  const float* bka   = (const float*)d_in[9];
  const float* Wv    = (const float*)d_in[10];
  const float* bv    = (const float*)d_in[11];
  const float* gamma = (const float*)d_in[12];
  const float* beta  = (const float*)d_in[13];
  float* out = (float*)d_out;

  char* ws = (char*)d_ws;
  const size_t MB = 1024 * 1024;
  // buffer plan (~171 MB total, with reuse):
  half_t* h16    = (half_t*)(ws + 0);         // 32MB: h, later reused as mixed16
  half_t* qkv16  = (half_t*)(ws + 32 * MB);   // 96MB: [16384][3072] q|k|v
  half_t* logits = (half_t*)(ws + 128 * MB);  // 32MB: logits; softmax runs in-place
  half_t* wcat   = (half_t*)(ws + 160 * MB);  // 6MB: [3072][1024] Wq|Wk|Wv transposed
  half_t* wqa16  = (half_t*)(ws + 166 * MB);  // 2MB
  half_t* wka16  = (half_t*)(ws + 168 * MB);  // 2MB
  float*  bcat   = (float*)(ws + 170 * MB);   // 12KB
  float*  part   = (float*)(ws + 170 * MB + 64 * 1024);  // 512KB

  half_t* q16 = qkv16;            // lda 3072
  half_t* k16 = qkv16 + 1024;
  half_t* v16 = qkv16 + 2048;
  half_t* mixed16 = h16;          // reuse (h dead after gemm1)
  half_t* sw = logits;            // softmax output in-place

  prep_w<<<5120, 256, 0, stream>>>(Wq, Wk, Wv, Wqa, Wka, wcat, wqa16, wka16);
  copy_bias<<<12, 256, 0, stream>>>(bq, bk, bv, bcat);
  ln_kernel<<<ROWS, 256, 0, stream>>>(x, gamma, beta, h16);
  // q|k|v = h @ [Wq|Wk|Wv] + b   (M=16384, N=3072, K=1024)
  gemm_f16<<<dim3(24, 128), 256, 0, stream>>>(h16, 1024, wcat, bcat, qkv16, 3072, 1024);
  // logits = q @ Wqa + bqa
  gemm_f16<<<dim3(8, 128), 256, 0, stream>>>(q16, 3072, wqa16, bqa, logits, 1024, 1024);
  softmax_k<<<ROWS, 256, 0, stream>>>(logits, sw);
  // mixed = (cumsum(qw.*q)/scale) .* k
  cs_partial<<<dim3(4, NC, BS), 256, 0, stream>>>(sw, 1024, q16, 3072, part);
  cs_apply<true><<<dim3(4, NC, BS), 256, 0, stream>>>(sw, 1024, q16, 3072, k16, 3072,
                                                      part, mixed16, nullptr);
  // logits = mixed @ Wka + bka
  gemm_f16<<<dim3(8, 128), 256, 0, stream>>>(mixed16, 1024, wka16, bka, logits, 1024, 1024);
  softmax_k<<<ROWS, 256, 0, stream>>>(logits, sw);
  // out = (cumsum(kw.*mixed)/scale) .* v
  cs_partial<<<dim3(4, NC, BS), 256, 0, stream>>>(sw, 1024, mixed16, 1024, part);
  cs_apply<false><<<dim3(4, NC, BS), 256, 0, stream>>>(sw, 1024, mixed16, 1024, v16, 3072,
                                                       part, nullptr, out);
}

// Round 2
// 321.657 us; speedup vs baseline: 1.2855x; 1.2855x over previous
//
#include <hip/hip_runtime.h>

typedef _Float16 half_t;
typedef _Float16 f16x8 __attribute__((ext_vector_type(8)));
typedef _Float16 f16x4 __attribute__((ext_vector_type(4)));
typedef float f32x4 __attribute__((ext_vector_type(4)));

#define D_MODEL 1024
#define BS 4
#define SEQ 4096
#define ROWS (BS * SEQ)   // 16384
#define SC 128
#define NC (SEQ / SC)     // 32

#define BARRIER() asm volatile("s_barrier" ::: "memory")
#define WAITV(n)  asm volatile("s_waitcnt vmcnt(" #n ")" ::: "memory")

__device__ __forceinline__ void gld_lds16(const half_t* g, char* l) {
  __builtin_amdgcn_global_load_lds((const __attribute__((address_space(1))) void*)g,
                                   (__attribute__((address_space(3))) void*)l, 16, 0, 0);
}

// ---------------- LayerNorm: fp32 in -> f16 out ----------------
__global__ __launch_bounds__(256) void ln_kernel(const float* __restrict__ x,
                                                 const float* __restrict__ gamma,
                                                 const float* __restrict__ beta,
                                                 half_t* __restrict__ h) {
  const int row = blockIdx.x;
  const int t = threadIdx.x;
  const float* xr = x + (size_t)row * D_MODEL + t * 4;
  f32x4 v = *(const f32x4*)xr;
  float s = v[0] + v[1] + v[2] + v[3];
  float q = v[0]*v[0] + v[1]*v[1] + v[2]*v[2] + v[3]*v[3];
#pragma unroll
  for (int off = 32; off > 0; off >>= 1) {
    s += __shfl_down(s, off, 64);
    q += __shfl_down(q, off, 64);
  }
  __shared__ float rs[4], rq[4];
  const int wv = t >> 6, ln = t & 63;
  if (ln == 0) { rs[wv] = s; rq[wv] = q; }
  __syncthreads();
  s = rs[0] + rs[1] + rs[2] + rs[3];
  q = rq[0] + rq[1] + rq[2] + rq[3];
  const float mu = s * (1.0f / D_MODEL);
  const float var = q * (1.0f / D_MODEL) - mu * mu;
  const float rstd = rsqrtf(var + 1e-5f);
  f32x4 g = *(const f32x4*)(gamma + t * 4);
  f32x4 b = *(const f32x4*)(beta + t * 4);
  f16x4 o;
#pragma unroll
  for (int i = 0; i < 4; i++) o[i] = (half_t)((v[i] - mu) * rstd * g[i] + b[i]);
  *(f16x4*)(h + (size_t)row * D_MODEL + t * 4) = o;
}

// ---------------- weight prepack: fp32 [K][N] -> f16 [N][K] ----------------
__global__ __launch_bounds__(256) void prep_w(const float* __restrict__ Wq,
                                              const float* __restrict__ Wk,
                                              const float* __restrict__ Wv,
                                              const float* __restrict__ Wqa,
                                              const float* __restrict__ Wka,
                                              half_t* __restrict__ wcat,
                                              half_t* __restrict__ wqa,
                                              half_t* __restrict__ wka) {
  const int b = blockIdx.x;
  const int mat = b >> 10;       // 5 matrices x 1024 tiles
  const int tile = b & 1023;
  const int tn = (tile & 31) * 32;
  const int tk = (tile >> 5) * 32;
  const float* W = mat == 0 ? Wq : mat == 1 ? Wk : mat == 2 ? Wv : mat == 3 ? Wqa : Wka;
  half_t* dst = mat < 3 ? wcat + (size_t)mat * D_MODEL * D_MODEL : (mat == 3 ? wqa : wka);
  __shared__ float tl[32][33];
  const int tx = threadIdx.x & 31, ty = threadIdx.x >> 5;
#pragma unroll
  for (int i = 0; i < 32; i += 8)
    tl[ty + i][tx] = W[(size_t)(tk + ty + i) * D_MODEL + tn + tx];
  __syncthreads();
#pragma unroll
  for (int i = 0; i < 32; i += 8)
    dst[(size_t)(tn + ty + i) * D_MODEL + tk + tx] = (half_t)tl[tx][ty + i];
}

__global__ __launch_bounds__(256) void copy_bias(const float* __restrict__ bq,
                                                 const float* __restrict__ bk,
                                                 const float* __restrict__ bv,
                                                 float* __restrict__ bcat) {
  const int i = blockIdx.x * 256 + threadIdx.x;
  if (i < 1024) bcat[i] = bq[i];
  else if (i < 2048) bcat[i] = bk[i - 1024];
  else if (i < 3072) bcat[i] = bv[i - 2048];
}

// ---------------- 256x256 8-phase MFMA GEMM, K=1024 fixed ----------------
// C[M][N] = A[M][K] @ Bt[N][K]^T + bias.  8 waves (2M x 4N), wave tile 128x64.
// LDS 128KB: 2 bufs x (A 256x64 + B 256x64) f16, granule-XOR swizzled.
// Schedule per iter (2 K-tiles a=2i[buf0], b=2i+1[buf1]); stages:
//   P1:A0(b) P2:A1(b) P3:B0(c) P4:B1(c)+vmcnt4 P5:A0(c) P6:A1(c) P7:B0(d) P8:B1(d)+vmcnt4
// with c=2i+2 (buf0), d=2i+3 (buf1).

#define STAGE_A(buf, h, kt) do { \
  gld_lds16(gA + (size_t)(h)*128*lda + (size_t)(kt)*64,        smem + (buf)*65536 + (h)*16384 + wid*1024); \
  gld_lds16(gA + ((size_t)(h)*128 + 64)*lda + (size_t)(kt)*64, smem + (buf)*65536 + (h)*16384 + 8192 + wid*1024); \
} while (0)

#define STAGE_B(buf, h, kt) do { \
  gld_lds16(gB + (size_t)(h)*128*1024 + (size_t)(kt)*64,        smem + (buf)*65536 + 32768 + (h)*16384 + wid*1024); \
  gld_lds16(gB + ((size_t)(h)*128 + 64)*1024 + (size_t)(kt)*64, smem + (buf)*65536 + 32768 + (h)*16384 + 8192 + wid*1024); \
} while (0)

#define LOAD_A(buf, base) do { \
  _Pragma("unroll") for (int _fm = 0; _fm < 4; ++_fm) { \
    aF[_fm][0] = *(const f16x8*)(smem + (buf)*65536 + rA + gsw0 + ((base)+_fm)*2048); \
    aF[_fm][1] = *(const f16x8*)(smem + (buf)*65536 + rA + gsw1 + ((base)+_fm)*2048); \
  } \
} while (0)

#define LOAD_B(dst, buf, base) do { \
  _Pragma("unroll") for (int _fn = 0; _fn < 2; ++_fn) { \
    dst[_fn][0] = *(const f16x8*)(smem + (buf)*65536 + 32768 + rB + gsw0 + ((base)+_fn)*2048); \
    dst[_fn][1] = *(const f16x8*)(smem + (buf)*65536 + 32768 + rB + gsw1 + ((base)+_fn)*2048); \
  } \
} while (0)

#define QUAD(BR, MOFF, NOFF) do { \
  __builtin_amdgcn_s_setprio(1); \
  _Pragma("unroll") for (int _fm = 0; _fm < 4; ++_fm) \
  _Pragma("unroll") for (int _fn = 0; _fn < 2; ++_fn) { \
    acc[(MOFF)+_fm][(NOFF)+_fn] = __builtin_amdgcn_mfma_f32_16x16x32_f16(aF[_fm][0], BR[_fn][0], acc[(MOFF)+_fm][(NOFF)+_fn], 0, 0, 0); \
    acc[(MOFF)+_fm][(NOFF)+_fn] = __builtin_amdgcn_mfma_f32_16x16x32_f16(aF[_fm][1], BR[_fn][1], acc[(MOFF)+_fm][(NOFF)+_fn], 0, 0, 0); \
  } \
  __builtin_amdgcn_s_setprio(0); \
} while (0)

__global__ __launch_bounds__(512, 2) void gemm8(const half_t* __restrict__ A, int lda,
                                                const half_t* __restrict__ Bt,
                                                const float* __restrict__ bias,
                                                half_t* __restrict__ C, int ldc) {
  extern __shared__ char smem[];
  const int t = threadIdx.x;
  const int ln = t & 63, wid = t >> 6;
  const int wm = wid >> 2, wn = wid & 3;

  // XCD-aware bijective block swizzle (nwg % 8 == 0 for all our grids)
  const int gx = gridDim.x;
  const int nwg = gx * gridDim.y;
  const int orig = blockIdx.y * gx + blockIdx.x;
  const int swz = (orig & 7) * (nwg >> 3) + (orig >> 3);
  const int bx = swz % gx, by = swz / gx;
  const int n0 = bx * 256, m0 = by * 256;

  // staging source (pre-swizzled granule so linear LDS dest lands swizzled)
  const int srow = t >> 3;               // 0..63
  const int sg = (t & 7) ^ (srow & 7);   // source granule for this thread's slot
  const half_t* gA = A + (size_t)(m0 + srow) * lda + sg * 8;
  const half_t* gB = Bt + (size_t)(n0 + srow) * 1024 + sg * 8;

  // fragment ds_read offsets (swizzled): row*128 + (granule ^ (row&7))*16
  const int rA = (wm * 128 + (ln & 15)) * 128;
  const int rB = (wn * 64 + (ln & 15)) * 128;
  const int gsw0 = (((ln >> 4)) ^ (ln & 7)) << 4;
  const int gsw1 = ((4 | (ln >> 4)) ^ (ln & 7)) << 4;

  f32x4 acc[8][4] = {};
  f16x8 aF[4][2], bL[2][2], bH[2][2];

  // prologue: kt0 all 4 halves -> buf0; kt1 B halves -> buf1
  STAGE_A(0, 0, 0); STAGE_A(0, 1, 0); STAGE_B(0, 0, 0); STAGE_B(0, 1, 0);
  STAGE_B(1, 0, 1); STAGE_B(1, 1, 1);
  WAITV(4); BARRIER();

#pragma unroll 1
  for (int i = 0; i < 8; ++i) {
    const int kb = 2 * i + 1;
    const int kc = 2 * i + 2;
    const int kd = 2 * i + 3;
    const bool f = (i < 7);
    // ---- P1: Q0 on buf0
    LOAD_A(0, 0);
    LOAD_B(bL, 0, 0);
    STAGE_A(1, 0, kb);
    BARRIER(); QUAD(bL, 0, 0); BARRIER();
    // ---- P2: Q1
    LOAD_B(bH, 0, 2);
    STAGE_A(1, 1, kb);
    BARRIER(); QUAD(bH, 0, 2); BARRIER();
    // ---- P3: Q2
    LOAD_A(0, 4);
    if (f) STAGE_B(0, 0, kc);
    BARRIER(); QUAD(bH, 4, 2); BARRIER();
    // ---- P4: Q3 (regs only) + K-tile wait
    if (f) { STAGE_B(0, 1, kc); WAITV(4); } else { WAITV(0); }
    BARRIER(); QUAD(bL, 4, 0); BARRIER();
    // ---- P5: Q0 on buf1
    LOAD_A(1, 0);
    LOAD_B(bL, 1, 0);
    if (f) STAGE_A(0, 0, kc);
    BARRIER(); QUAD(bL, 0, 0); BARRIER();
    // ---- P6: Q1
    LOAD_B(bH, 1, 2);
    if (f) STAGE_A(0, 1, kc);
    BARRIER(); QUAD(bH, 0, 2); BARRIER();
    // ---- P7: Q2
    LOAD_A(1, 4);
    if (f) STAGE_B(1, 0, kd);
    BARRIER(); QUAD(bH, 4, 2); BARRIER();
    // ---- P8: Q3 + K-tile wait
    if (f) { STAGE_B(1, 1, kd); WAITV(4); }
    BARRIER(); QUAD(bL, 4, 0); BARRIER();
  }

  // epilogue: C/D layout col=ln&15, row=(ln>>4)*4+r
  const int r0 = m0 + wm * 128 + ((ln >> 4) << 2);
  const int c0 = n0 + wn * 64 + (ln & 15);
  float bb[4];
#pragma unroll
  for (int fn = 0; fn < 4; ++fn) bb[fn] = bias[c0 + fn * 16];
#pragma unroll
  for (int fm = 0; fm < 8; ++fm)
#pragma unroll
    for (int fn = 0; fn < 4; ++fn) {
      const int col = c0 + fn * 16;
      const int row = r0 + fm * 16;
#pragma unroll
      for (int r = 0; r < 4; ++r)
        C[(size_t)(row + r) * ldc + col] = (half_t)(acc[fm][fn][r] + bb[fn]);
    }
}

// ---------------- row softmax over D=1024, logits scaled 1/32 ----------------
__global__ __launch_bounds__(256) void softmax_k(const half_t* __restrict__ L,
                                                 half_t* __restrict__ O) {
  const size_t row = blockIdx.x;
  const int t = threadIdx.x;
  f16x4 v = *(const f16x4*)(L + row * D_MODEL + t * 4);
  float x[4];
#pragma unroll
  for (int i = 0; i < 4; i++) x[i] = (float)v[i] * 0.03125f;  // 1/sqrt(1024)
  float mx = fmaxf(fmaxf(x[0], x[1]), fmaxf(x[2], x[3]));
#pragma unroll
  for (int off = 32; off > 0; off >>= 1) mx = fmaxf(mx, __shfl_xor(mx, off, 64));
  __shared__ float sm[4], ssum[4];
  const int wv = t >> 6, ln = t & 63;
  if (ln == 0) sm[wv] = mx;
  __syncthreads();
  mx = fmaxf(fmaxf(sm[0], sm[1]), fmaxf(sm[2], sm[3]));
  float e[4]; float s = 0.f;
#pragma unroll
  for (int i = 0; i < 4; i++) { e[i] = expf(x[i] - mx); s += e[i]; }
#pragma unroll
  for (int off = 32; off > 0; off >>= 1) s += __shfl_xor(s, off, 64);
  if (ln == 0) ssum[wv] = s;
  __syncthreads();
  s = ssum[0] + ssum[1] + ssum[2] + ssum[3];
  const float r = 1.0f / s;
  f16x4 o;
#pragma unroll
  for (int i = 0; i < 4; i++) o[i] = (half_t)(e[i] * r);
  *(f16x4*)(O + row * D_MODEL + t * 4) = o;
}

// ---------------- cumsum pass 1: per-chunk partial sums of A.*B ----------------
__global__ __launch_bounds__(256) void cs_partial(const half_t* __restrict__ A, int ldA,
                                                  const half_t* __restrict__ B, int ldB,
                                                  float* __restrict__ part) {
  const int d = blockIdx.x * 256 + threadIdx.x;
  const int c = blockIdx.y;
  const int bb = blockIdx.z;
  const size_t s0 = (size_t)bb * SEQ + (size_t)c * SC;
  const half_t* pa = A + s0 * ldA + d;
  const half_t* pb = B + s0 * ldB + d;
  float acc = 0.f;
#pragma unroll 8
  for (int s = 0; s < SC; s++) acc += (float)pa[(size_t)s * ldA] * (float)pb[(size_t)s * ldB];
  part[((size_t)bb * NC + c) * D_MODEL + d] = acc;
}

// ---------------- cumsum pass 2 ----------------
template <bool HALF_OUT>
__global__ __launch_bounds__(256) void cs_apply(const half_t* __restrict__ A, int ldA,
                                                const half_t* __restrict__ B, int ldB,
                                                const half_t* __restrict__ Cm, int ldC,
                                                const float* __restrict__ part,
                                                half_t* __restrict__ OH,
                                                float* __restrict__ OF) {
  const int d = blockIdx.x * 256 + threadIdx.x;
  const int c = blockIdx.y;
  const int bb = blockIdx.z;
  float acc = 0.f;
  for (int cc = 0; cc < c; cc++) acc += part[((size_t)bb * NC + cc) * D_MODEL + d];
  const size_t s0 = (size_t)bb * SEQ + (size_t)c * SC;
#pragma unroll 4
  for (int s = 0; s < SC; s++) {
    const size_t sg = s0 + s;
    acc += (float)A[sg * ldA + d] * (float)B[sg * ldB + d];
    const float pooled = acc / (float)(c * SC + s + 1);
    const float m = pooled * (float)Cm[sg * ldC + d];
    if (HALF_OUT) OH[sg * D_MODEL + d] = (half_t)m;
    else          OF[sg * D_MODEL + d] = m;
  }
}

extern "C" void kernel_launch(void* const* d_in, const int* in_sizes, int n_in,
                              void* d_out, int out_size, void* d_ws, size_t ws_size,
                              hipStream_t stream) {
  const float* x     = (const float*)d_in[0];
  const float* Wq    = (const float*)d_in[2];
  const float* bq    = (const float*)d_in[3];
  const float* Wqa   = (const float*)d_in[4];
  const float* bqa   = (const float*)d_in[5];
  const float* Wk    = (const float*)d_in[6];
  const float* bk    = (const float*)d_in[7];
  const float* Wka   = (const float*)d_in[8];
  const float* bka   = (const float*)d_in[9];
  const float* Wv    = (const float*)d_in[10];
  const float* bv    = (const float*)d_in[11];
  const float* gamma = (const float*)d_in[12];
  const float* beta  = (const float*)d_in[13];
  float* out = (float*)d_out;

  char* ws = (char*)d_ws;
  const size_t MB = 1024 * 1024;
  half_t* h16    = (half_t*)(ws + 0);         // 32MB: h, later reused as mixed16
  half_t* qkv16  = (half_t*)(ws + 32 * MB);   // 96MB: [16384][3072] q|k|v
  half_t* logits = (half_t*)(ws + 128 * MB);  // 32MB: logits; softmax in-place
  half_t* wcat   = (half_t*)(ws + 160 * MB);  // 6MB: [3072][1024] Wq|Wk|Wv transposed
  half_t* wqa16  = (half_t*)(ws + 166 * MB);  // 2MB
  half_t* wka16  = (half_t*)(ws + 168 * MB);  // 2MB
  float*  bcat   = (float*)(ws + 170 * MB);   // 12KB
  float*  part   = (float*)(ws + 170 * MB + 64 * 1024);  // 512KB

  half_t* q16 = qkv16;            // lda 3072
  half_t* k16 = qkv16 + 1024;
  half_t* v16 = qkv16 + 2048;
  half_t* mixed16 = h16;          // reuse (h dead after gemm1)
  half_t* sw = logits;            // softmax output in-place

  hipFuncSetAttribute((const void*)gemm8, hipFuncAttributeMaxDynamicSharedMemorySize, 131072);

  prep_w<<<5120, 256, 0, stream>>>(Wq, Wk, Wv, Wqa, Wka, wcat, wqa16, wka16);
  copy_bias<<<12, 256, 0, stream>>>(bq, bk, bv, bcat);
  ln_kernel<<<ROWS, 256, 0, stream>>>(x, gamma, beta, h16);
  // q|k|v = h @ [Wq|Wk|Wv] + b   (M=16384, N=3072, K=1024)
  gemm8<<<dim3(12, 64), 512, 131072, stream>>>(h16, 1024, wcat, bcat, qkv16, 3072);
  // logits = q @ Wqa + bqa
  gemm8<<<dim3(4, 64), 512, 131072, stream>>>(q16, 3072, wqa16, bqa, logits, 1024);
  softmax_k<<<ROWS, 256, 0, stream>>>(logits, sw);
  // mixed = (cumsum(qw.*q)/scale) .* k
  cs_partial<<<dim3(4, NC, BS), 256, 0, stream>>>(sw, 1024, q16, 3072, part);
  cs_apply<true><<<dim3(4, NC, BS), 256, 0, stream>>>(sw, 1024, q16, 3072, k16, 3072,
                                                      part, mixed16, nullptr);
  // logits = mixed @ Wka + bka
  gemm8<<<dim3(4, 64), 512, 131072, stream>>>(mixed16, 1024, wka16, bka, logits, 1024);
  softmax_k<<<ROWS, 256, 0, stream>>>(logits, sw);
  // out = (cumsum(kw.*mixed)/scale) .* v
  cs_partial<<<dim3(4, NC, BS), 256, 0, stream>>>(sw, 1024, mixed16, 1024, part);
  cs_apply<false><<<dim3(4, NC, BS), 256, 0, stream>>>(sw, 1024, mixed16, 1024, v16, 3072,
                                                       part, nullptr, out);
}

// Round 3
// 225.334 us; speedup vs baseline: 1.8350x; 1.4275x over previous
//
#include <hip/hip_runtime.h>

typedef _Float16 half_t;
typedef _Float16 f16x8 __attribute__((ext_vector_type(8)));
typedef _Float16 f16x4 __attribute__((ext_vector_type(4)));
typedef float f32x4 __attribute__((ext_vector_type(4)));

#define D_MODEL 1024
#define BS 4
#define SEQ 4096
#define ROWS (BS * SEQ)   // 16384
#define SC 128
#define NC (SEQ / SC)     // 32

#define BARRIER() asm volatile("s_barrier" ::: "memory")
#define WAITV(n)  asm volatile("s_waitcnt vmcnt(" #n ")" ::: "memory")

__device__ __forceinline__ void gld_lds16(const half_t* g, char* l) {
  __builtin_amdgcn_global_load_lds((const __attribute__((address_space(1))) void*)g,
                                   (__attribute__((address_space(3))) void*)l, 16, 0, 0);
}

// ---------------- flags: detect all-zero weight matrices ----------------
__global__ void zero_flags(int* f) {
  if (threadIdx.x < 2) f[threadIdx.x] = 0;
}

// 512 blocks: 0-255 -> W0/flag[0], 256-511 -> W1/flag[1]; OR of all bits.
__global__ __launch_bounds__(256) void detect_nz(const float* __restrict__ W0,
                                                 const float* __restrict__ W1,
                                                 int* __restrict__ flags) {
  const int which = blockIdx.x >> 8;
  const unsigned* w = (const unsigned*)(which ? W1 : W0);
  const int blk = blockIdx.x & 255;
  unsigned v = 0;
  const size_t base = (size_t)blk * 4096 + threadIdx.x;
#pragma unroll
  for (int i = 0; i < 16; ++i) v |= w[base + i * 256];
#pragma unroll
  for (int off = 32; off > 0; off >>= 1) v |= __shfl_down(v, off, 64);
  __shared__ unsigned sv[4];
  if ((threadIdx.x & 63) == 0) sv[threadIdx.x >> 6] = v;
  __syncthreads();
  if (threadIdx.x == 0) {
    v = sv[0] | sv[1] | sv[2] | sv[3];
    if (v) atomicOr(&flags[which], 1);
  }
}

// ---------------- softmax of (bias/32): one 1024-vector per bias, f32 ----------------
__global__ __launch_bounds__(256) void bias_softmax(const float* __restrict__ bqa,
                                                    const float* __restrict__ bka,
                                                    float* __restrict__ qwv,
                                                    float* __restrict__ kwv) {
  const float* b = blockIdx.x ? bka : bqa;
  float* o = blockIdx.x ? kwv : qwv;
  const int t = threadIdx.x;
  f32x4 v = *(const f32x4*)(b + t * 4);
  float x[4];
#pragma unroll
  for (int i = 0; i < 4; i++) x[i] = v[i] * 0.03125f;
  float mx = fmaxf(fmaxf(x[0], x[1]), fmaxf(x[2], x[3]));
#pragma unroll
  for (int off = 32; off > 0; off >>= 1) mx = fmaxf(mx, __shfl_xor(mx, off, 64));
  __shared__ float sm[4], ssum[4];
  const int wv = t >> 6, ln = t & 63;
  if (ln == 0) sm[wv] = mx;
  __syncthreads();
  mx = fmaxf(fmaxf(sm[0], sm[1]), fmaxf(sm[2], sm[3]));
  float e[4]; float s = 0.f;
#pragma unroll
  for (int i = 0; i < 4; i++) { e[i] = expf(x[i] - mx); s += e[i]; }
#pragma unroll
  for (int off = 32; off > 0; off >>= 1) s += __shfl_xor(s, off, 64);
  if (ln == 0) ssum[wv] = s;
  __syncthreads();
  s = ssum[0] + ssum[1] + ssum[2] + ssum[3];
  const float r = 1.0f / s;
  f32x4 ov;
#pragma unroll
  for (int i = 0; i < 4; i++) ov[i] = e[i] * r;
  *(f32x4*)(o + t * 4) = ov;
}

// ---------------- LayerNorm: fp32 in -> f16 out ----------------
__global__ __launch_bounds__(256) void ln_kernel(const float* __restrict__ x,
                                                 const float* __restrict__ gamma,
                                                 const float* __restrict__ beta,
                                                 half_t* __restrict__ h) {
  const int row = blockIdx.x;
  const int t = threadIdx.x;
  const float* xr = x + (size_t)row * D_MODEL + t * 4;
  f32x4 v = *(const f32x4*)xr;
  float s = v[0] + v[1] + v[2] + v[3];
  float q = v[0]*v[0] + v[1]*v[1] + v[2]*v[2] + v[3]*v[3];
#pragma unroll
  for (int off = 32; off > 0; off >>= 1) {
    s += __shfl_down(s, off, 64);
    q += __shfl_down(q, off, 64);
  }
  __shared__ float rs[4], rq[4];
  const int wv = t >> 6, ln = t & 63;
  if (ln == 0) { rs[wv] = s; rq[wv] = q; }
  __syncthreads();
  s = rs[0] + rs[1] + rs[2] + rs[3];
  q = rq[0] + rq[1] + rq[2] + rq[3];
  const float mu = s * (1.0f / D_MODEL);
  const float var = q * (1.0f / D_MODEL) - mu * mu;
  const float rstd = rsqrtf(var + 1e-5f);
  f32x4 g = *(const f32x4*)(gamma + t * 4);
  f32x4 b = *(const f32x4*)(beta + t * 4);
  f16x4 o;
#pragma unroll
  for (int i = 0; i < 4; i++) o[i] = (half_t)((v[i] - mu) * rstd * g[i] + b[i]);
  *(f16x4*)(h + (size_t)row * D_MODEL + t * 4) = o;
}

// ---------------- weight prepack: fp32 [K][N] -> f16 [N][K] ----------------
__global__ __launch_bounds__(256) void prep_w(const float* __restrict__ Wq,
                                              const float* __restrict__ Wk,
                                              const float* __restrict__ Wv,
                                              const float* __restrict__ Wqa,
                                              const float* __restrict__ Wka,
                                              half_t* __restrict__ wcat,
                                              half_t* __restrict__ wqa,
                                              half_t* __restrict__ wka) {
  const int b = blockIdx.x;
  const int mat = b >> 10;
  const int tile = b & 1023;
  const int tn = (tile & 31) * 32;
  const int tk = (tile >> 5) * 32;
  const float* W = mat == 0 ? Wq : mat == 1 ? Wk : mat == 2 ? Wv : mat == 3 ? Wqa : Wka;
  half_t* dst = mat < 3 ? wcat + (size_t)mat * D_MODEL * D_MODEL : (mat == 3 ? wqa : wka);
  __shared__ float tl[32][33];
  const int tx = threadIdx.x & 31, ty = threadIdx.x >> 5;
#pragma unroll
  for (int i = 0; i < 32; i += 8)
    tl[ty + i][tx] = W[(size_t)(tk + ty + i) * D_MODEL + tn + tx];
  __syncthreads();
#pragma unroll
  for (int i = 0; i < 32; i += 8)
    dst[(size_t)(tn + ty + i) * D_MODEL + tk + tx] = (half_t)tl[tx][ty + i];
}

__global__ __launch_bounds__(256) void copy_bias(const float* __restrict__ bq,
                                                 const float* __restrict__ bk,
                                                 const float* __restrict__ bv,
                                                 float* __restrict__ bcat) {
  const int i = blockIdx.x * 256 + threadIdx.x;
  if (i < 1024) bcat[i] = bq[i];
  else if (i < 2048) bcat[i] = bk[i - 1024];
  else if (i < 3072) bcat[i] = bv[i - 2048];
}

// ---------------- 256x256 8-phase MFMA GEMM, K=1024 fixed ----------------
// Stage slots re-derived from region-free times (B-half free after 2nd read
// phase, A-half after 3rd): P3:B(c) P4:A(c)+vmcnt8  P7:B(d) P8:A(d)+vmcnt8.
// Every half-tile lands >=4 phases before its consumption wait.

#define STAGE_A(buf, h, kt) do { \
  gld_lds16(gA + (size_t)(h)*128*lda + (size_t)(kt)*64,        smem + (buf)*65536 + (h)*16384 + wid*1024); \
  gld_lds16(gA + ((size_t)(h)*128 + 64)*lda + (size_t)(kt)*64, smem + (buf)*65536 + (h)*16384 + 8192 + wid*1024); \
} while (0)

#define STAGE_B(buf, h, kt) do { \
  gld_lds16(gB + (size_t)(h)*128*1024 + (size_t)(kt)*64,        smem + (buf)*65536 + 32768 + (h)*16384 + wid*1024); \
  gld_lds16(gB + ((size_t)(h)*128 + 64)*1024 + (size_t)(kt)*64, smem + (buf)*65536 + 32768 + (h)*16384 + 8192 + wid*1024); \
} while (0)

#define LOAD_A(buf, base) do { \
  _Pragma("unroll") for (int _fm = 0; _fm < 4; ++_fm) { \
    aF[_fm][0] = *(const f16x8*)(smem + (buf)*65536 + rA + gsw0 + ((base)+_fm)*2048); \
    aF[_fm][1] = *(const f16x8*)(smem + (buf)*65536 + rA + gsw1 + ((base)+_fm)*2048); \
  } \
} while (0)

#define LOAD_B(dst, buf, base) do { \
  _Pragma("unroll") for (int _fn = 0; _fn < 2; ++_fn) { \
    dst[_fn][0] = *(const f16x8*)(smem + (buf)*65536 + 32768 + rB + gsw0 + ((base)+_fn)*2048); \
    dst[_fn][1] = *(const f16x8*)(smem + (buf)*65536 + 32768 + rB + gsw1 + ((base)+_fn)*2048); \
  } \
} while (0)

#define QUAD(BR, MOFF, NOFF) do { \
  __builtin_amdgcn_s_setprio(1); \
  _Pragma("unroll") for (int _fm = 0; _fm < 4; ++_fm) \
  _Pragma("unroll") for (int _fn = 0; _fn < 2; ++_fn) { \
    acc[(MOFF)+_fm][(NOFF)+_fn] = __builtin_amdgcn_mfma_f32_16x16x32_f16(aF[_fm][0], BR[_fn][0], acc[(MOFF)+_fm][(NOFF)+_fn], 0, 0, 0); \
    acc[(MOFF)+_fm][(NOFF)+_fn] = __builtin_amdgcn_mfma_f32_16x16x32_f16(aF[_fm][1], BR[_fn][1], acc[(MOFF)+_fm][(NOFF)+_fn], 0, 0, 0); \
  } \
  __builtin_amdgcn_s_setprio(0); \
} while (0)

__global__ __launch_bounds__(512, 2) void gemm8(const half_t* __restrict__ A, int lda,
                                                const half_t* __restrict__ Bt,
                                                const float* __restrict__ bias,
                                                half_t* __restrict__ C, int ldc,
                                                const int* skip) {
  if (skip && *skip == 0) return;   // all-zero weight: result unused downstream
  extern __shared__ char smem[];
  const int t = threadIdx.x;
  const int ln = t & 63, wid = t >> 6;
  const int wm = wid >> 2, wn = wid & 3;

  const int gx = gridDim.x;
  const int nwg = gx * gridDim.y;
  const int orig = blockIdx.y * gx + blockIdx.x;
  const int swz = (orig & 7) * (nwg >> 3) + (orig >> 3);
  const int bx = swz % gx, by = swz / gx;
  const int n0 = bx * 256, m0 = by * 256;

  const int srow = t >> 3;
  const int sg = (t & 7) ^ (srow & 7);
  const half_t* gA = A + (size_t)(m0 + srow) * lda + sg * 8;
  const half_t* gB = Bt + (size_t)(n0 + srow) * 1024 + sg * 8;

  const int rA = (wm * 128 + (ln & 15)) * 128;
  const int rB = (wn * 64 + (ln & 15)) * 128;
  const int gsw0 = (((ln >> 4)) ^ (ln & 7)) << 4;
  const int gsw1 = ((4 | (ln >> 4)) ^ (ln & 7)) << 4;

  f32x4 acc[8][4] = {};
  f16x8 aF[4][2], bL[2][2], bH[2][2];

  // prologue: tile0 (buf0) B+A, tile1 (buf1) B+A; wait tile0 (keep tile1's 8)
  STAGE_B(0, 0, 0); STAGE_B(0, 1, 0); STAGE_A(0, 0, 0); STAGE_A(0, 1, 0);
  STAGE_B(1, 0, 1); STAGE_B(1, 1, 1); STAGE_A(1, 0, 1); STAGE_A(1, 1, 1);
  WAITV(8); BARRIER();

#pragma unroll 1
  for (int i = 0; i < 8; ++i) {
    const int kc = 2 * i + 2;
    const int kd = 2 * i + 3;
    const bool f = (i < 7);
    // ---- P1: Q0 on buf0
    LOAD_A(0, 0);
    LOAD_B(bL, 0, 0);
    BARRIER(); QUAD(bL, 0, 0); BARRIER();
    // ---- P2: Q1
    LOAD_B(bH, 0, 2);
    BARRIER(); QUAD(bH, 0, 2); BARRIER();
    // ---- P3: Q2 ; buf0 B region free -> stage B(c)
    LOAD_A(0, 4);
    if (f) { STAGE_B(0, 0, kc); STAGE_B(0, 1, kc); }
    BARRIER(); QUAD(bH, 4, 2); BARRIER();
    // ---- P4: Q3 ; buf0 A free -> stage A(c); wait tile-b landed (keep 8)
    if (f) { STAGE_A(0, 0, kc); STAGE_A(0, 1, kc); WAITV(8); } else WAITV(0);
    BARRIER(); QUAD(bL, 4, 0); BARRIER();
    // ---- P5: Q0 on buf1
    LOAD_A(1, 0);
    LOAD_B(bL, 1, 0);
    BARRIER(); QUAD(bL, 0, 0); BARRIER();
    // ---- P6: Q1
    LOAD_B(bH, 1, 2);
    BARRIER(); QUAD(bH, 0, 2); BARRIER();
    // ---- P7: Q2 ; buf1 B free -> stage B(d)
    LOAD_A(1, 4);
    if (f) { STAGE_B(1, 0, kd); STAGE_B(1, 1, kd); }
    BARRIER(); QUAD(bH, 4, 2); BARRIER();
    // ---- P8: Q3 ; buf1 A free -> stage A(d); wait tile-c landed (keep 8)
    if (f) { STAGE_A(1, 0, kd); STAGE_A(1, 1, kd); WAITV(8); } else WAITV(0);
    BARRIER(); QUAD(bL, 4, 0); BARRIER();
  }

  const int r0 = m0 + wm * 128 + ((ln >> 4) << 2);
  const int c0 = n0 + wn * 64 + (ln & 15);
  float bb[4];
#pragma unroll
  for (int fn = 0; fn < 4; ++fn) bb[fn] = bias[c0 + fn * 16];
#pragma unroll
  for (int fm = 0; fm < 8; ++fm)
#pragma unroll
    for (int fn = 0; fn < 4; ++fn) {
      const int col = c0 + fn * 16;
      const int row = r0 + fm * 16;
#pragma unroll
      for (int r = 0; r < 4; ++r)
        C[(size_t)(row + r) * ldc + col] = (half_t)(acc[fm][fn][r] + bb[fn]);
    }
}

// ---------------- row softmax over D=1024, logits scaled 1/32 ----------------
__global__ __launch_bounds__(256) void softmax_k(const half_t* __restrict__ L,
                                                 half_t* __restrict__ O,
                                                 const int* skip) {
  if (skip && *skip == 0) return;
  const size_t row = blockIdx.x;
  const int t = threadIdx.x;
  f16x4 v = *(const f16x4*)(L + row * D_MODEL + t * 4);
  float x[4];
#pragma unroll
  for (int i = 0; i < 4; i++) x[i] = (float)v[i] * 0.03125f;
  float mx = fmaxf(fmaxf(x[0], x[1]), fmaxf(x[2], x[3]));
#pragma unroll
  for (int off = 32; off > 0; off >>= 1) mx = fmaxf(mx, __shfl_xor(mx, off, 64));
  __shared__ float sm[4], ssum[4];
  const int wv = t >> 6, ln = t & 63;
  if (ln == 0) sm[wv] = mx;
  __syncthreads();
  mx = fmaxf(fmaxf(sm[0], sm[1]), fmaxf(sm[2], sm[3]));
  float e[4]; float s = 0.f;
#pragma unroll
  for (int i = 0; i < 4; i++) { e[i] = expf(x[i] - mx); s += e[i]; }
#pragma unroll
  for (int off = 32; off > 0; off >>= 1) s += __shfl_xor(s, off, 64);
  if (ln == 0) ssum[wv] = s;
  __syncthreads();
  s = ssum[0] + ssum[1] + ssum[2] + ssum[3];
  const float r = 1.0f / s;
  f16x4 o;
#pragma unroll
  for (int i = 0; i < 4; i++) o[i] = (half_t)(e[i] * r);
  *(f16x4*)(O + row * D_MODEL + t * 4) = o;
}

// ---------------- cumsum pass 1: per-chunk partial sums of w.*B ----------------
__global__ __launch_bounds__(256) void cs_partial(const int* __restrict__ nz,
                                                  const float* __restrict__ wv,
                                                  const half_t* __restrict__ A, int ldA,
                                                  const half_t* __restrict__ B, int ldB,
                                                  float* __restrict__ part) {
  const int d = blockIdx.x * 256 + threadIdx.x;
  const int c = blockIdx.y;
  const int bb = blockIdx.z;
  const size_t s0 = (size_t)bb * SEQ + (size_t)c * SC;
  const half_t* pa = A + s0 * ldA + d;
  const half_t* pb = B + s0 * ldB + d;
  float acc = 0.f;
  if (*nz == 0) {
    const float w = wv[d];
#pragma unroll 8
    for (int s = 0; s < SC; s++) acc += w * (float)pb[(size_t)s * ldB];
  } else {
#pragma unroll 8
    for (int s = 0; s < SC; s++) acc += (float)pa[(size_t)s * ldA] * (float)pb[(size_t)s * ldB];
  }
  part[((size_t)bb * NC + c) * D_MODEL + d] = acc;
}

// ---------------- cumsum pass 1 for stage 2: shortcut uses msum ----------------
__global__ __launch_bounds__(256) void cs_partial2(const int* __restrict__ nz,
                                                   const float* __restrict__ wv,
                                                   const float* __restrict__ msum,
                                                   const half_t* __restrict__ A, int ldA,
                                                   const half_t* __restrict__ B, int ldB,
                                                   float* __restrict__ part) {
  const int d = blockIdx.x * 256 + threadIdx.x;
  const int c = blockIdx.y;
  const int bb = blockIdx.z;
  const size_t idx = ((size_t)bb * NC + c) * D_MODEL + d;
  if (*nz == 0) {
    part[idx] = wv[d] * msum[idx];
    return;
  }
  const size_t s0 = (size_t)bb * SEQ + (size_t)c * SC;
  const half_t* pa = A + s0 * ldA + d;
  const half_t* pb = B + s0 * ldB + d;
  float acc = 0.f;
#pragma unroll 8
  for (int s = 0; s < SC; s++) acc += (float)pa[(size_t)s * ldA] * (float)pb[(size_t)s * ldB];
  part[idx] = acc;
}

// ---------------- cumsum pass 2: prefix + in-chunk scan, out = pooled .* Cm ----------------
template <bool HALF_OUT>
__global__ __launch_bounds__(256) void cs_apply(const int* __restrict__ nz,
                                                const float* __restrict__ wv,
                                                const half_t* __restrict__ A, int ldA,
                                                const half_t* __restrict__ B, int ldB,
                                                const half_t* __restrict__ Cm, int ldC,
                                                const float* __restrict__ part,
                                                float* __restrict__ msum,
                                                half_t* __restrict__ OH,
                                                float* __restrict__ OF) {
  const int d = blockIdx.x * 256 + threadIdx.x;
  const int c = blockIdx.y;
  const int bb = blockIdx.z;
  float acc = 0.f;
  for (int cc = 0; cc < c; cc++) acc += part[((size_t)bb * NC + cc) * D_MODEL + d];
  const size_t s0 = (size_t)bb * SEQ + (size_t)c * SC;
  float ms = 0.f;
  if (*nz == 0) {
    const float w = wv[d];
#pragma unroll 4
    for (int s = 0; s < SC; s++) {
      const size_t sg = s0 + s;
      acc += w * (float)B[sg * ldB + d];
      const float pooled = acc / (float)(c * SC + s + 1);
      const float m = pooled * (float)Cm[sg * ldC + d];
      ms += m;
      if (HALF_OUT) OH[sg * D_MODEL + d] = (half_t)m;
      else          OF[sg * D_MODEL + d] = m;
    }
  } else {
#pragma unroll 4
    for (int s = 0; s < SC; s++) {
      const size_t sg = s0 + s;
      acc += (float)A[sg * ldA + d] * (float)B[sg * ldB + d];
      const float pooled = acc / (float)(c * SC + s + 1);
      const float m = pooled * (float)Cm[sg * ldC + d];
      ms += m;
      if (HALF_OUT) OH[sg * D_MODEL + d] = (half_t)m;
      else          OF[sg * D_MODEL + d] = m;
    }
  }
  if (msum) msum[((size_t)bb * NC + c) * D_MODEL + d] = ms;
}

extern "C" void kernel_launch(void* const* d_in, const int* in_sizes, int n_in,
                              void* d_out, int out_size, void* d_ws, size_t ws_size,
                              hipStream_t stream) {
  const float* x     = (const float*)d_in[0];
  const float* Wq    = (const float*)d_in[2];
  const float* bq    = (const float*)d_in[3];
  const float* Wqa   = (const float*)d_in[4];
  const float* bqa   = (const float*)d_in[5];
  const float* Wk    = (const float*)d_in[6];
  const float* bk    = (const float*)d_in[7];
  const float* Wka   = (const float*)d_in[8];
  const float* bka   = (const float*)d_in[9];
  const float* Wv    = (const float*)d_in[10];
  const float* bv    = (const float*)d_in[11];
  const float* gamma = (const float*)d_in[12];
  const float* beta  = (const float*)d_in[13];
  float* out = (float*)d_out;

  char* ws = (char*)d_ws;
  const size_t MB = 1024 * 1024;
  half_t* h16    = (half_t*)(ws + 0);         // 32MB: h, later reused as mixed16
  half_t* qkv16  = (half_t*)(ws + 32 * MB);   // 96MB: [16384][3072] q|k|v
  half_t* logits = (half_t*)(ws + 128 * MB);  // 32MB: logits; softmax in-place
  half_t* wcat   = (half_t*)(ws + 160 * MB);  // 6MB
  half_t* wqa16  = (half_t*)(ws + 166 * MB);  // 2MB
  half_t* wka16  = (half_t*)(ws + 168 * MB);  // 2MB
  float*  bcat   = (float*)(ws + 170 * MB);   // 12KB
  float*  part   = (float*)(ws + 170 * MB + 64 * 1024);   // 512KB
  float*  msum   = (float*)(ws + 170 * MB + 1024 * 1024); // 512KB
  float*  qwv    = (float*)(ws + 170 * MB + 1600 * 1024); // 4KB
  float*  kwv    = (float*)(ws + 170 * MB + 1604 * 1024); // 4KB
  int*    flags  = (int*)(ws + 170 * MB + 1608 * 1024);   // 8B

  half_t* q16 = qkv16;            // lda 3072
  half_t* k16 = qkv16 + 1024;
  half_t* v16 = qkv16 + 2048;
  half_t* mixed16 = h16;          // reuse (h dead after gemm1)
  half_t* sw = logits;            // softmax output in-place

  hipFuncSetAttribute((const void*)gemm8, hipFuncAttributeMaxDynamicSharedMemorySize, 131072);

  zero_flags<<<1, 64, 0, stream>>>(flags);
  detect_nz<<<512, 256, 0, stream>>>(Wqa, Wka, flags);
  bias_softmax<<<2, 256, 0, stream>>>(bqa, bka, qwv, kwv);
  prep_w<<<5120, 256, 0, stream>>>(Wq, Wk, Wv, Wqa, Wka, wcat, wqa16, wka16);
  copy_bias<<<12, 256, 0, stream>>>(bq, bk, bv, bcat);
  ln_kernel<<<ROWS, 256, 0, stream>>>(x, gamma, beta, h16);
  // q|k|v = h @ [Wq|Wk|Wv] + b   (M=16384, N=3072, K=1024)
  gemm8<<<dim3(12, 64), 512, 131072, stream>>>(h16, 1024, wcat, bcat, qkv16, 3072, nullptr);
  // logits = q @ Wqa + bqa  (skipped when Wqa == 0)
  gemm8<<<dim3(4, 64), 512, 131072, stream>>>(q16, 3072, wqa16, bqa, logits, 1024, flags);
  softmax_k<<<ROWS, 256, 0, stream>>>(logits, sw, flags);
  // mixed = (cumsum(qw.*q)/scale) .* k
  cs_partial<<<dim3(4, NC, BS), 256, 0, stream>>>(flags, qwv, sw, 1024, q16, 3072, part);
  cs_apply<true><<<dim3(4, NC, BS), 256, 0, stream>>>(flags, qwv, sw, 1024, q16, 3072,
                                                      k16, 3072, part, msum, mixed16, nullptr);
  // logits = mixed @ Wka + bka  (skipped when Wka == 0)
  gemm8<<<dim3(4, 64), 512, 131072, stream>>>(mixed16, 1024, wka16, bka, logits, 1024, flags + 1);
  softmax_k<<<ROWS, 256, 0, stream>>>(logits, sw, flags + 1);
  // out = (cumsum(kw.*mixed)/scale) .* v
  cs_partial2<<<dim3(4, NC, BS), 256, 0, stream>>>(flags + 1, kwv, msum, sw, 1024,
                                                   mixed16, 1024, part);
  cs_apply<false><<<dim3(4, NC, BS), 256, 0, stream>>>(flags + 1, kwv, sw, 1024, mixed16, 1024,
                                                       v16, 3072, part, nullptr, nullptr, out);
}

// Round 4
// 224.350 us; speedup vs baseline: 1.8430x; 1.0044x over previous
//
#include <hip/hip_runtime.h>

typedef _Float16 half_t;
typedef _Float16 f16x8 __attribute__((ext_vector_type(8)));
typedef _Float16 f16x4 __attribute__((ext_vector_type(4)));
typedef float f32x4 __attribute__((ext_vector_type(4)));

#define D_MODEL 1024
#define BS 4
#define SEQ 4096
#define ROWS (BS * SEQ)   // 16384
#define SC 128
#define NC (SEQ / SC)     // 32

#define BARRIER() asm volatile("s_barrier" ::: "memory")
#define WAITV(n)  asm volatile("s_waitcnt vmcnt(" #n ")" ::: "memory")

__device__ __forceinline__ void gld_lds16(const half_t* g, char* l) {
  __builtin_amdgcn_global_load_lds((const __attribute__((address_space(1))) void*)g,
                                   (__attribute__((address_space(3))) void*)l, 16, 0, 0);
}

// ---------------- flags: detect all-zero weight matrices ----------------
__global__ void zero_flags(int* f) {
  if (threadIdx.x < 2) f[threadIdx.x] = 0;
}

__global__ __launch_bounds__(256) void detect_nz(const float* __restrict__ W0,
                                                 const float* __restrict__ W1,
                                                 int* __restrict__ flags) {
  const int which = blockIdx.x >> 8;
  const unsigned* w = (const unsigned*)(which ? W1 : W0);
  const int blk = blockIdx.x & 255;
  unsigned v = 0;
  const size_t base = (size_t)blk * 4096 + threadIdx.x;
#pragma unroll
  for (int i = 0; i < 16; ++i) v |= w[base + i * 256];
#pragma unroll
  for (int off = 32; off > 0; off >>= 1) v |= __shfl_down(v, off, 64);
  __shared__ unsigned sv[4];
  if ((threadIdx.x & 63) == 0) sv[threadIdx.x >> 6] = v;
  __syncthreads();
  if (threadIdx.x == 0) {
    v = sv[0] | sv[1] | sv[2] | sv[3];
    if (v) atomicOr(&flags[which], 1);
  }
}

// ---------------- softmax of (bias/32): one 1024-vector per bias, f32 ----------------
__global__ __launch_bounds__(256) void bias_softmax(const float* __restrict__ bqa,
                                                    const float* __restrict__ bka,
                                                    float* __restrict__ qwv,
                                                    float* __restrict__ kwv) {
  const float* b = blockIdx.x ? bka : bqa;
  float* o = blockIdx.x ? kwv : qwv;
  const int t = threadIdx.x;
  f32x4 v = *(const f32x4*)(b + t * 4);
  float x[4];
#pragma unroll
  for (int i = 0; i < 4; i++) x[i] = v[i] * 0.03125f;
  float mx = fmaxf(fmaxf(x[0], x[1]), fmaxf(x[2], x[3]));
#pragma unroll
  for (int off = 32; off > 0; off >>= 1) mx = fmaxf(mx, __shfl_xor(mx, off, 64));
  __shared__ float sm[4], ssum[4];
  const int wv = t >> 6, ln = t & 63;
  if (ln == 0) sm[wv] = mx;
  __syncthreads();
  mx = fmaxf(fmaxf(sm[0], sm[1]), fmaxf(sm[2], sm[3]));
  float e[4]; float s = 0.f;
#pragma unroll
  for (int i = 0; i < 4; i++) { e[i] = expf(x[i] - mx); s += e[i]; }
#pragma unroll
  for (int off = 32; off > 0; off >>= 1) s += __shfl_xor(s, off, 64);
  if (ln == 0) ssum[wv] = s;
  __syncthreads();
  s = ssum[0] + ssum[1] + ssum[2] + ssum[3];
  const float r = 1.0f / s;
  f32x4 ov;
#pragma unroll
  for (int i = 0; i < 4; i++) ov[i] = e[i] * r;
  *(f32x4*)(o + t * 4) = ov;
}

// ---------------- LayerNorm: fp32 in -> f16 out ----------------
__global__ __launch_bounds__(256) void ln_kernel(const float* __restrict__ x,
                                                 const float* __restrict__ gamma,
                                                 const float* __restrict__ beta,
                                                 half_t* __restrict__ h) {
  const int row = blockIdx.x;
  const int t = threadIdx.x;
  const float* xr = x + (size_t)row * D_MODEL + t * 4;
  f32x4 v = *(const f32x4*)xr;
  float s = v[0] + v[1] + v[2] + v[3];
  float q = v[0]*v[0] + v[1]*v[1] + v[2]*v[2] + v[3]*v[3];
#pragma unroll
  for (int off = 32; off > 0; off >>= 1) {
    s += __shfl_down(s, off, 64);
    q += __shfl_down(q, off, 64);
  }
  __shared__ float rs[4], rq[4];
  const int wv = t >> 6, ln = t & 63;
  if (ln == 0) { rs[wv] = s; rq[wv] = q; }
  __syncthreads();
  s = rs[0] + rs[1] + rs[2] + rs[3];
  q = rq[0] + rq[1] + rq[2] + rq[3];
  const float mu = s * (1.0f / D_MODEL);
  const float var = q * (1.0f / D_MODEL) - mu * mu;
  const float rstd = rsqrtf(var + 1e-5f);
  f32x4 g = *(const f32x4*)(gamma + t * 4);
  f32x4 b = *(const f32x4*)(beta + t * 4);
  f16x4 o;
#pragma unroll
  for (int i = 0; i < 4; i++) o[i] = (half_t)((v[i] - mu) * rstd * g[i] + b[i]);
  *(f16x4*)(h + (size_t)row * D_MODEL + t * 4) = o;
}

// ---------------- weight prepack: fp32 [K][N] -> f16 [N][K] ----------------
__global__ __launch_bounds__(256) void prep_w(const float* __restrict__ Wq,
                                              const float* __restrict__ Wk,
                                              const float* __restrict__ Wv,
                                              const float* __restrict__ Wqa,
                                              const float* __restrict__ Wka,
                                              half_t* __restrict__ wcat,
                                              half_t* __restrict__ wqa,
                                              half_t* __restrict__ wka) {
  const int b = blockIdx.x;
  const int mat = b >> 10;
  const int tile = b & 1023;
  const int tn = (tile & 31) * 32;
  const int tk = (tile >> 5) * 32;
  const float* W = mat == 0 ? Wq : mat == 1 ? Wk : mat == 2 ? Wv : mat == 3 ? Wqa : Wka;
  half_t* dst = mat < 3 ? wcat + (size_t)mat * D_MODEL * D_MODEL : (mat == 3 ? wqa : wka);
  __shared__ float tl[32][33];
  const int tx = threadIdx.x & 31, ty = threadIdx.x >> 5;
#pragma unroll
  for (int i = 0; i < 32; i += 8)
    tl[ty + i][tx] = W[(size_t)(tk + ty + i) * D_MODEL + tn + tx];
  __syncthreads();
#pragma unroll
  for (int i = 0; i < 32; i += 8)
    dst[(size_t)(tn + ty + i) * D_MODEL + tk + tx] = (half_t)tl[tx][ty + i];
}

__global__ __launch_bounds__(256) void copy_bias(const float* __restrict__ bq,
                                                 const float* __restrict__ bk,
                                                 const float* __restrict__ bv,
                                                 float* __restrict__ bcat) {
  const int i = blockIdx.x * 256 + threadIdx.x;
  if (i < 1024) bcat[i] = bq[i];
  else if (i < 2048) bcat[i] = bk[i - 1024];
  else if (i < 3072) bcat[i] = bv[i - 2048];
}

// ---------------- 256x256 8-phase MFMA GEMM, K=1024 fixed ----------------
// Uniform staging: ONE half-tile (2 gld_lds) per phase, vmcnt(6) at P4/P8 only.
// Halves are row-striped to match region-free times of the quadrant order:
//   Aα = A rows [0,64)∪[128,192)   (free after P1/P5 reads)
//   Aβ = A rows [64,128)∪[192,256) (free after P3/P7)
//   Bγ = B rows ∪wn wn*64+[0,32)   (free after P1/P5)
//   Bδ = B rows ∪wn wn*64+[32,64)  (free after P2/P6)
// Slots: P1:Bδ(b) P2:Aα(c) P3:Bγ(c) P4:Aβ(c)+w6 P5:Bδ(c) P6:Aα(d) P7:Bγ(d) P8:Aβ(d)+w6

#define SA2(buf, rb, kt) do { \
  gld_lds16(gA + (size_t)((rb) + wbA + r8) * lda + (size_t)(kt) * 64 + grn * 8, \
            smem + (buf)*65536 + ((rb) + wbA) * 128); \
  gld_lds16(gA + (size_t)((rb) + 128 + wbA + r8) * lda + (size_t)(kt) * 64 + grn * 8, \
            smem + (buf)*65536 + ((rb) + 128 + wbA) * 128); \
} while (0)

#define SB2(buf, gd, kt) do { \
  gld_lds16(gB + (size_t)((gd) + wbB + r8) * 1024 + (size_t)(kt) * 64 + grn * 8, \
            smem + (buf)*65536 + 32768 + ((gd) + wbB) * 128); \
  gld_lds16(gB + (size_t)((gd) + 128 + wbB + r8) * 1024 + (size_t)(kt) * 64 + grn * 8, \
            smem + (buf)*65536 + 32768 + ((gd) + 128 + wbB) * 128); \
} while (0)

#define LOAD_A(buf, base) do { \
  _Pragma("unroll") for (int _fm = 0; _fm < 4; ++_fm) { \
    aF[_fm][0] = *(const f16x8*)(smem + (buf)*65536 + rA + gsw0 + ((base)+_fm)*2048); \
    aF[_fm][1] = *(const f16x8*)(smem + (buf)*65536 + rA + gsw1 + ((base)+_fm)*2048); \
  } \
} while (0)

#define LOAD_B(dst, buf, base) do { \
  _Pragma("unroll") for (int _fn = 0; _fn < 2; ++_fn) { \
    dst[_fn][0] = *(const f16x8*)(smem + (buf)*65536 + 32768 + rB + gsw0 + ((base)+_fn)*2048); \
    dst[_fn][1] = *(const f16x8*)(smem + (buf)*65536 + 32768 + rB + gsw1 + ((base)+_fn)*2048); \
  } \
} while (0)

#define QUAD(BR, MOFF, NOFF) do { \
  __builtin_amdgcn_s_setprio(1); \
  _Pragma("unroll") for (int _fm = 0; _fm < 4; ++_fm) \
  _Pragma("unroll") for (int _fn = 0; _fn < 2; ++_fn) { \
    acc[(MOFF)+_fm][(NOFF)+_fn] = __builtin_amdgcn_mfma_f32_16x16x32_f16(aF[_fm][0], BR[_fn][0], acc[(MOFF)+_fm][(NOFF)+_fn], 0, 0, 0); \
    acc[(MOFF)+_fm][(NOFF)+_fn] = __builtin_amdgcn_mfma_f32_16x16x32_f16(aF[_fm][1], BR[_fn][1], acc[(MOFF)+_fm][(NOFF)+_fn], 0, 0, 0); \
  } \
  __builtin_amdgcn_s_setprio(0); \
} while (0)

__global__ __launch_bounds__(512, 2) void gemm8(const half_t* __restrict__ A, int lda,
                                                const half_t* __restrict__ Bt,
                                                const float* __restrict__ bias,
                                                half_t* __restrict__ C, int ldc,
                                                const int* skip) {
  if (skip && *skip == 0) return;
  extern __shared__ char smem[];
  const int t = threadIdx.x;
  const int ln = t & 63, wid = t >> 6;
  const int wm = wid >> 2, wn = wid & 3;

  const int gx = gridDim.x;
  const int nwg = gx * gridDim.y;
  const int orig = blockIdx.y * gx + blockIdx.x;
  const int swz = (orig & 7) * (nwg >> 3) + (orig >> 3);
  const int bx = swz % gx, by = swz / gx;
  const int n0 = bx * 256, m0 = by * 256;

  // staging per-thread geometry (wave bases are multiples of 8, so the
  // granule pre-swizzle (t&7)^r8 is row-correct for every line)
  const int r8 = (t >> 3) & 7;
  const int grn = (t & 7) ^ r8;
  const int wbA = wid * 8;
  const int wbB = ((wid >> 2) << 6) + (wid & 3) * 8;
  const half_t* gA = A + (size_t)m0 * lda;
  const half_t* gB = Bt + (size_t)n0 * 1024;

  const int rA = (wm * 128 + (ln & 15)) * 128;
  const int rB = (wn * 64 + (ln & 15)) * 128;
  const int gsw0 = (((ln >> 4)) ^ (ln & 7)) << 4;
  const int gsw1 = ((4 | (ln >> 4)) ^ (ln & 7)) << 4;

  f32x4 acc[8][4] = {};
  f16x8 aF[4][2], bL[2][2], bH[2][2];

  // prologue: tile0 complete (4 halves), tile1 Aα,Bγ,Aβ (Bδ(1) staged at i=0 P1)
  SA2(0, 0, 0); SB2(0, 0, 0); SA2(0, 64, 0); SB2(0, 32, 0);
  SA2(1, 0, 1); SB2(1, 0, 1); SA2(1, 64, 1);
  WAITV(6); BARRIER();

#pragma unroll 1
  for (int i = 0; i < 8; ++i) {
    const int kb = 2 * i + 1;
    const int kc = 2 * i + 2;
    const int kd = 2 * i + 3;
    const bool f = (i < 7);
    // ---- P1: Q0 buf0 (m0-3 x n0-1); stage Bδ(b)
    LOAD_A(0, 0); LOAD_B(bL, 0, 0);
    SB2(1, 32, kb);
    BARRIER(); QUAD(bL, 0, 0); BARRIER();
    // ---- P2: Q1 (m0-3 x n2-3); stage Aα(c)
    LOAD_B(bH, 0, 2);
    if (f) SA2(0, 0, kc);
    BARRIER(); QUAD(bH, 0, 2); BARRIER();
    // ---- P3: Q2 (m4-7 x n2-3); stage Bγ(c)
    LOAD_A(0, 4);
    if (f) SB2(0, 0, kc);
    BARRIER(); QUAD(bH, 4, 2); BARRIER();
    // ---- P4: Q3 (m4-7 x n0-1); stage Aβ(c); counted wait
    if (f) { SA2(0, 64, kc); WAITV(6); } else WAITV(0);
    BARRIER(); QUAD(bL, 4, 0); BARRIER();
    // ---- P5: Q0 buf1; stage Bδ(c)
    LOAD_A(1, 0); LOAD_B(bL, 1, 0);
    if (f) SB2(0, 32, kc);
    BARRIER(); QUAD(bL, 0, 0); BARRIER();
    // ---- P6: Q1; stage Aα(d)
    LOAD_B(bH, 1, 2);
    if (f) SA2(1, 0, kd);
    BARRIER(); QUAD(bH, 0, 2); BARRIER();
    // ---- P7: Q2; stage Bγ(d)
    LOAD_A(1, 4);
    if (f) SB2(1, 0, kd);
    BARRIER(); QUAD(bH, 4, 2); BARRIER();
    // ---- P8: Q3; stage Aβ(d); counted wait
    if (f) { SA2(1, 64, kd); WAITV(6); }
    BARRIER(); QUAD(bL, 4, 0); BARRIER();
  }

  const int r0 = m0 + wm * 128 + ((ln >> 4) << 2);
  const int c0 = n0 + wn * 64 + (ln & 15);
  float bb[4];
#pragma unroll
  for (int fn = 0; fn < 4; ++fn) bb[fn] = bias[c0 + fn * 16];
#pragma unroll
  for (int fm = 0; fm < 8; ++fm)
#pragma unroll
    for (int fn = 0; fn < 4; ++fn) {
      const int col = c0 + fn * 16;
      const int row = r0 + fm * 16;
#pragma unroll
      for (int r = 0; r < 4; ++r)
        C[(size_t)(row + r) * ldc + col] = (half_t)(acc[fm][fn][r] + bb[fn]);
    }
}

// ---------------- row softmax over D=1024, logits scaled 1/32 ----------------
__global__ __launch_bounds__(256) void softmax_k(const half_t* __restrict__ L,
                                                 half_t* __restrict__ O,
                                                 const int* skip) {
  if (skip && *skip == 0) return;
  const size_t row = blockIdx.x;
  const int t = threadIdx.x;
  f16x4 v = *(const f16x4*)(L + row * D_MODEL + t * 4);
  float x[4];
#pragma unroll
  for (int i = 0; i < 4; i++) x[i] = (float)v[i] * 0.03125f;
  float mx = fmaxf(fmaxf(x[0], x[1]), fmaxf(x[2], x[3]));
#pragma unroll
  for (int off = 32; off > 0; off >>= 1) mx = fmaxf(mx, __shfl_xor(mx, off, 64));
  __shared__ float sm[4], ssum[4];
  const int wv = t >> 6, ln = t & 63;
  if (ln == 0) sm[wv] = mx;
  __syncthreads();
  mx = fmaxf(fmaxf(sm[0], sm[1]), fmaxf(sm[2], sm[3]));
  float e[4]; float s = 0.f;
#pragma unroll
  for (int i = 0; i < 4; i++) { e[i] = expf(x[i] - mx); s += e[i]; }
#pragma unroll
  for (int off = 32; off > 0; off >>= 1) s += __shfl_xor(s, off, 64);
  if (ln == 0) ssum[wv] = s;
  __syncthreads();
  s = ssum[0] + ssum[1] + ssum[2] + ssum[3];
  const float r = 1.0f / s;
  f16x4 o;
#pragma unroll
  for (int i = 0; i < 4; i++) o[i] = (half_t)(e[i] * r);
  *(f16x4*)(O + row * D_MODEL + t * 4) = o;
}

// ---------------- cumsum pass 1 ----------------
__global__ __launch_bounds__(256) void cs_partial(const int* __restrict__ nz,
                                                  const float* __restrict__ wv,
                                                  const half_t* __restrict__ A, int ldA,
                                                  const half_t* __restrict__ B, int ldB,
                                                  float* __restrict__ part) {
  const int d = blockIdx.x * 256 + threadIdx.x;
  const int c = blockIdx.y;
  const int bb = blockIdx.z;
  const size_t s0 = (size_t)bb * SEQ + (size_t)c * SC;
  const half_t* pa = A + s0 * ldA + d;
  const half_t* pb = B + s0 * ldB + d;
  float acc = 0.f;
  if (*nz == 0) {
    const float w = wv[d];
#pragma unroll 8
    for (int s = 0; s < SC; s++) acc += w * (float)pb[(size_t)s * ldB];
  } else {
#pragma unroll 8
    for (int s = 0; s < SC; s++) acc += (float)pa[(size_t)s * ldA] * (float)pb[(size_t)s * ldB];
  }
  part[((size_t)bb * NC + c) * D_MODEL + d] = acc;
}

// ---------------- cumsum pass 1 for stage 2 (shortcut uses msum) ----------------
__global__ __launch_bounds__(256) void cs_partial2(const int* __restrict__ nz,
                                                   const float* __restrict__ wv,
                                                   const float* __restrict__ msum,
                                                   const half_t* __restrict__ A, int ldA,
                                                   const half_t* __restrict__ B, int ldB,
                                                   float* __restrict__ part) {
  const int d = blockIdx.x * 256 + threadIdx.x;
  const int c = blockIdx.y;
  const int bb = blockIdx.z;
  const size_t idx = ((size_t)bb * NC + c) * D_MODEL + d;
  if (*nz == 0) {
    part[idx] = wv[d] * msum[idx];
    return;
  }
  const size_t s0 = (size_t)bb * SEQ + (size_t)c * SC;
  const half_t* pa = A + s0 * ldA + d;
  const half_t* pb = B + s0 * ldB + d;
  float acc = 0.f;
#pragma unroll 8
  for (int s = 0; s < SC; s++) acc += (float)pa[(size_t)s * ldA] * (float)pb[(size_t)s * ldB];
  part[idx] = acc;
}

// ---------------- cumsum pass 2 ----------------
template <bool HALF_OUT>
__global__ __launch_bounds__(256) void cs_apply(const int* __restrict__ nz,
                                                const float* __restrict__ wv,
                                                const half_t* __restrict__ A, int ldA,
                                                const half_t* __restrict__ B, int ldB,
                                                const half_t* __restrict__ Cm, int ldC,
                                                const float* __restrict__ part,
                                                float* __restrict__ msum,
                                                half_t* __restrict__ OH,
                                                float* __restrict__ OF) {
  const int d = blockIdx.x * 256 + threadIdx.x;
  const int c = blockIdx.y;
  const int bb = blockIdx.z;
  float acc = 0.f;
  for (int cc = 0; cc < c; cc++) acc += part[((size_t)bb * NC + cc) * D_MODEL + d];
  const size_t s0 = (size_t)bb * SEQ + (size_t)c * SC;
  float ms = 0.f;
  if (*nz == 0) {
    const float w = wv[d];
#pragma unroll 4
    for (int s = 0; s < SC; s++) {
      const size_t sg = s0 + s;
      acc += w * (float)B[sg * ldB + d];
      const float pooled = acc / (float)(c * SC + s + 1);
      const float m = pooled * (float)Cm[sg * ldC + d];
      ms += m;
      if (HALF_OUT) OH[sg * D_MODEL + d] = (half_t)m;
      else          OF[sg * D_MODEL + d] = m;
    }
  } else {
#pragma unroll 4
    for (int s = 0; s < SC; s++) {
      const size_t sg = s0 + s;
      acc += (float)A[sg * ldA + d] * (float)B[sg * ldB + d];
      const float pooled = acc / (float)(c * SC + s + 1);
      const float m = pooled * (float)Cm[sg * ldC + d];
      ms += m;
      if (HALF_OUT) OH[sg * D_MODEL + d] = (half_t)m;
      else          OF[sg * D_MODEL + d] = m;
    }
  }
  if (msum) msum[((size_t)bb * NC + c) * D_MODEL + d] = ms;
}

extern "C" void kernel_launch(void* const* d_in, const int* in_sizes, int n_in,
                              void* d_out, int out_size, void* d_ws, size_t ws_size,
                              hipStream_t stream) {
  const float* x     = (const float*)d_in[0];
  const float* Wq    = (const float*)d_in[2];
  const float* bq    = (const float*)d_in[3];
  const float* Wqa   = (const float*)d_in[4];
  const float* bqa   = (const float*)d_in[5];
  const float* Wk    = (const float*)d_in[6];
  const float* bk    = (const float*)d_in[7];
  const float* Wka   = (const float*)d_in[8];
  const float* bka   = (const float*)d_in[9];
  const float* Wv    = (const float*)d_in[10];
  const float* bv    = (const float*)d_in[11];
  const float* gamma = (const float*)d_in[12];
  const float* beta  = (const float*)d_in[13];
  float* out = (float*)d_out;

  char* ws = (char*)d_ws;
  const size_t MB = 1024 * 1024;
  half_t* h16    = (half_t*)(ws + 0);         // 32MB: h, later reused as mixed16
  half_t* qkv16  = (half_t*)(ws + 32 * MB);   // 96MB: [16384][3072] q|k|v
  half_t* logits = (half_t*)(ws + 128 * MB);  // 32MB
  half_t* wcat   = (half_t*)(ws + 160 * MB);  // 6MB
  half_t* wqa16  = (half_t*)(ws + 166 * MB);  // 2MB
  half_t* wka16  = (half_t*)(ws + 168 * MB);  // 2MB
  float*  bcat   = (float*)(ws + 170 * MB);   // 12KB
  float*  part   = (float*)(ws + 170 * MB + 64 * 1024);   // 512KB
  float*  msum   = (float*)(ws + 170 * MB + 1024 * 1024); // 512KB
  float*  qwv    = (float*)(ws + 170 * MB + 1600 * 1024); // 4KB
  float*  kwv    = (float*)(ws + 170 * MB + 1604 * 1024); // 4KB
  int*    flags  = (int*)(ws + 170 * MB + 1608 * 1024);   // 8B

  half_t* q16 = qkv16;            // lda 3072
  half_t* k16 = qkv16 + 1024;
  half_t* v16 = qkv16 + 2048;
  half_t* mixed16 = h16;
  half_t* sw = logits;

  hipFuncSetAttribute((const void*)gemm8, hipFuncAttributeMaxDynamicSharedMemorySize, 131072);

  zero_flags<<<1, 64, 0, stream>>>(flags);
  detect_nz<<<512, 256, 0, stream>>>(Wqa, Wka, flags);
  bias_softmax<<<2, 256, 0, stream>>>(bqa, bka, qwv, kwv);
  prep_w<<<5120, 256, 0, stream>>>(Wq, Wk, Wv, Wqa, Wka, wcat, wqa16, wka16);
  copy_bias<<<12, 256, 0, stream>>>(bq, bk, bv, bcat);
  ln_kernel<<<ROWS, 256, 0, stream>>>(x, gamma, beta, h16);
  // q|k|v = h @ [Wq|Wk|Wv] + b   (M=16384, N=3072, K=1024)
  gemm8<<<dim3(12, 64), 512, 131072, stream>>>(h16, 1024, wcat, bcat, qkv16, 3072, nullptr);
  // logits = q @ Wqa + bqa  (skipped when Wqa == 0)
  gemm8<<<dim3(4, 64), 512, 131072, stream>>>(q16, 3072, wqa16, bqa, logits, 1024, flags);
  softmax_k<<<ROWS, 256, 0, stream>>>(logits, sw, flags);
  // mixed = (cumsum(qw.*q)/scale) .* k
  cs_partial<<<dim3(4, NC, BS), 256, 0, stream>>>(flags, qwv, sw, 1024, q16, 3072, part);
  cs_apply<true><<<dim3(4, NC, BS), 256, 0, stream>>>(flags, qwv, sw, 1024, q16, 3072,
                                                      k16, 3072, part, msum, mixed16, nullptr);
  // logits = mixed @ Wka + bka  (skipped when Wka == 0)
  gemm8<<<dim3(4, 64), 512, 131072, stream>>>(mixed16, 1024, wka16, bka, logits, 1024, flags + 1);
  softmax_k<<<ROWS, 256, 0, stream>>>(logits, sw, flags + 1);
  // out = (cumsum(kw.*mixed)/scale) .* v
  cs_partial2<<<dim3(4, NC, BS), 256, 0, stream>>>(flags + 1, kwv, msum, sw, 1024,
                                                   mixed16, 1024, part);
  cs_apply<false><<<dim3(4, NC, BS), 256, 0, stream>>>(flags + 1, kwv, sw, 1024, mixed16, 1024,
                                                       v16, 3072, part, nullptr, nullptr, out);
}

// Round 5
// 222.665 us; speedup vs baseline: 1.8570x; 1.0076x over previous
//
#include <hip/hip_runtime.h>

typedef _Float16 half_t;
typedef _Float16 f16x8 __attribute__((ext_vector_type(8)));
typedef _Float16 f16x4 __attribute__((ext_vector_type(4)));
typedef float f32x4 __attribute__((ext_vector_type(4)));

#define D_MODEL 1024
#define BS 4
#define SEQ 4096
#define ROWS (BS * SEQ)   // 16384
#define SC 128
#define NC (SEQ / SC)     // 32

#define BARRIER() asm volatile("s_barrier" ::: "memory")
#define WAITV(n)  asm volatile("s_waitcnt vmcnt(" #n ")" ::: "memory")

__device__ __forceinline__ void gld_lds16(const half_t* g, char* l) {
  __builtin_amdgcn_global_load_lds((const __attribute__((address_space(1))) void*)g,
                                   (__attribute__((address_space(3))) void*)l, 16, 0, 0);
}

// ---------------- flags: detect all-zero weight matrices ----------------
__global__ void zero_flags(int* f) {
  if (threadIdx.x < 2) f[threadIdx.x] = 0;
}

__global__ __launch_bounds__(256) void detect_nz(const float* __restrict__ W0,
                                                 const float* __restrict__ W1,
                                                 int* __restrict__ flags) {
  const int which = blockIdx.x >> 8;
  const unsigned* w = (const unsigned*)(which ? W1 : W0);
  const int blk = blockIdx.x & 255;
  unsigned v = 0;
  const size_t base = (size_t)blk * 4096 + threadIdx.x;
#pragma unroll
  for (int i = 0; i < 16; ++i) v |= w[base + i * 256];
#pragma unroll
  for (int off = 32; off > 0; off >>= 1) v |= __shfl_down(v, off, 64);
  __shared__ unsigned sv[4];
  if ((threadIdx.x & 63) == 0) sv[threadIdx.x >> 6] = v;
  __syncthreads();
  if (threadIdx.x == 0) {
    v = sv[0] | sv[1] | sv[2] | sv[3];
    if (v) atomicOr(&flags[which], 1);
  }
}

// ---------------- softmax of (bias/32): one 1024-vector per bias, f32 ----------------
__global__ __launch_bounds__(256) void bias_softmax(const float* __restrict__ bqa,
                                                    const float* __restrict__ bka,
                                                    float* __restrict__ qwv,
                                                    float* __restrict__ kwv) {
  const float* b = blockIdx.x ? bka : bqa;
  float* o = blockIdx.x ? kwv : qwv;
  const int t = threadIdx.x;
  f32x4 v = *(const f32x4*)(b + t * 4);
  float x[4];
#pragma unroll
  for (int i = 0; i < 4; i++) x[i] = v[i] * 0.03125f;
  float mx = fmaxf(fmaxf(x[0], x[1]), fmaxf(x[2], x[3]));
#pragma unroll
  for (int off = 32; off > 0; off >>= 1) mx = fmaxf(mx, __shfl_xor(mx, off, 64));
  __shared__ float sm[4], ssum[4];
  const int wv = t >> 6, ln = t & 63;
  if (ln == 0) sm[wv] = mx;
  __syncthreads();
  mx = fmaxf(fmaxf(sm[0], sm[1]), fmaxf(sm[2], sm[3]));
  float e[4]; float s = 0.f;
#pragma unroll
  for (int i = 0; i < 4; i++) { e[i] = expf(x[i] - mx); s += e[i]; }
#pragma unroll
  for (int off = 32; off > 0; off >>= 1) s += __shfl_xor(s, off, 64);
  if (ln == 0) ssum[wv] = s;
  __syncthreads();
  s = ssum[0] + ssum[1] + ssum[2] + ssum[3];
  const float r = 1.0f / s;
  f32x4 ov;
#pragma unroll
  for (int i = 0; i < 4; i++) ov[i] = e[i] * r;
  *(f32x4*)(o + t * 4) = ov;
}

// ---------------- LayerNorm: fp32 in -> f16 out ----------------
__global__ __launch_bounds__(256) void ln_kernel(const float* __restrict__ x,
                                                 const float* __restrict__ gamma,
                                                 const float* __restrict__ beta,
                                                 half_t* __restrict__ h) {
  const int row = blockIdx.x;
  const int t = threadIdx.x;
  const float* xr = x + (size_t)row * D_MODEL + t * 4;
  f32x4 v = *(const f32x4*)xr;
  float s = v[0] + v[1] + v[2] + v[3];
  float q = v[0]*v[0] + v[1]*v[1] + v[2]*v[2] + v[3]*v[3];
#pragma unroll
  for (int off = 32; off > 0; off >>= 1) {
    s += __shfl_down(s, off, 64);
    q += __shfl_down(q, off, 64);
  }
  __shared__ float rs[4], rq[4];
  const int wv = t >> 6, ln = t & 63;
  if (ln == 0) { rs[wv] = s; rq[wv] = q; }
  __syncthreads();
  s = rs[0] + rs[1] + rs[2] + rs[3];
  q = rq[0] + rq[1] + rq[2] + rq[3];
  const float mu = s * (1.0f / D_MODEL);
  const float var = q * (1.0f / D_MODEL) - mu * mu;
  const float rstd = rsqrtf(var + 1e-5f);
  f32x4 g = *(const f32x4*)(gamma + t * 4);
  f32x4 b = *(const f32x4*)(beta + t * 4);
  f16x4 o;
#pragma unroll
  for (int i = 0; i < 4; i++) o[i] = (half_t)((v[i] - mu) * rstd * g[i] + b[i]);
  *(f16x4*)(h + (size_t)row * D_MODEL + t * 4) = o;
}

// ---------------- weight prepack: fp32 [K][N] -> f16 [N][K] ----------------
__global__ __launch_bounds__(256) void prep_w(const float* __restrict__ Wq,
                                              const float* __restrict__ Wk,
                                              const float* __restrict__ Wv,
                                              const float* __restrict__ Wqa,
                                              const float* __restrict__ Wka,
                                              half_t* __restrict__ wcat,
                                              half_t* __restrict__ wqa,
                                              half_t* __restrict__ wka) {
  const int b = blockIdx.x;
  const int mat = b >> 10;
  const int tile = b & 1023;
  const int tn = (tile & 31) * 32;
  const int tk = (tile >> 5) * 32;
  const float* W = mat == 0 ? Wq : mat == 1 ? Wk : mat == 2 ? Wv : mat == 3 ? Wqa : Wka;
  half_t* dst = mat < 3 ? wcat + (size_t)mat * D_MODEL * D_MODEL : (mat == 3 ? wqa : wka);
  __shared__ float tl[32][33];
  const int tx = threadIdx.x & 31, ty = threadIdx.x >> 5;
#pragma unroll
  for (int i = 0; i < 32; i += 8)
    tl[ty + i][tx] = W[(size_t)(tk + ty + i) * D_MODEL + tn + tx];
  __syncthreads();
#pragma unroll
  for (int i = 0; i < 32; i += 8)
    dst[(size_t)(tn + ty + i) * D_MODEL + tk + tx] = (half_t)tl[tx][ty + i];
}

__global__ __launch_bounds__(256) void copy_bias(const float* __restrict__ bq,
                                                 const float* __restrict__ bk,
                                                 const float* __restrict__ bv,
                                                 float* __restrict__ bcat) {
  const int i = blockIdx.x * 256 + threadIdx.x;
  if (i < 1024) bcat[i] = bq[i];
  else if (i < 2048) bcat[i] = bk[i - 1024];
  else if (i < 3072) bcat[i] = bv[i - 2048];
}

// ---------------- 256x256 8-phase MFMA GEMM, K=1024 fixed ----------------
// One barrier per phase (end only): reads/stages/MFMAs co-schedule within a
// phase; waves skew so one wave's MFMA covers another's LDS reads.
// Stage slots (R4, re-audited): P1:Bδ(b) P2:Aα(c) P3:Bγ(c) P4:Aβ(c)+w6
//                               P5:Bδ(c) P6:Aα(d) P7:Bγ(d) P8:Aβ(d)+w6

#define SA2(buf, rb, kt) do { \
  gld_lds16(gA + (size_t)((rb) + wbA + r8) * lda + (size_t)(kt) * 64 + grn * 8, \
            smem + (buf)*65536 + ((rb) + wbA) * 128); \
  gld_lds16(gA + (size_t)((rb) + 128 + wbA + r8) * lda + (size_t)(kt) * 64 + grn * 8, \
            smem + (buf)*65536 + ((rb) + 128 + wbA) * 128); \
} while (0)

#define SB2(buf, gd, kt) do { \
  gld_lds16(gB + (size_t)((gd) + wbB + r8) * 1024 + (size_t)(kt) * 64 + grn * 8, \
            smem + (buf)*65536 + 32768 + ((gd) + wbB) * 128); \
  gld_lds16(gB + (size_t)((gd) + 128 + wbB + r8) * 1024 + (size_t)(kt) * 64 + grn * 8, \
            smem + (buf)*65536 + 32768 + ((gd) + 128 + wbB) * 128); \
} while (0)

#define LOAD_A(buf, base) do { \
  _Pragma("unroll") for (int _fm = 0; _fm < 4; ++_fm) { \
    aF[_fm][0] = *(const f16x8*)(smem + (buf)*65536 + rA + gsw0 + ((base)+_fm)*2048); \
    aF[_fm][1] = *(const f16x8*)(smem + (buf)*65536 + rA + gsw1 + ((base)+_fm)*2048); \
  } \
} while (0)

#define LOAD_B(dst, buf, base) do { \
  _Pragma("unroll") for (int _fn = 0; _fn < 2; ++_fn) { \
    dst[_fn][0] = *(const f16x8*)(smem + (buf)*65536 + 32768 + rB + gsw0 + ((base)+_fn)*2048); \
    dst[_fn][1] = *(const f16x8*)(smem + (buf)*65536 + 32768 + rB + gsw1 + ((base)+_fn)*2048); \
  } \
} while (0)

#define QUAD(BR, MOFF, NOFF) do { \
  __builtin_amdgcn_s_setprio(1); \
  _Pragma("unroll") for (int _fm = 0; _fm < 4; ++_fm) \
  _Pragma("unroll") for (int _fn = 0; _fn < 2; ++_fn) { \
    acc[(MOFF)+_fm][(NOFF)+_fn] = __builtin_amdgcn_mfma_f32_16x16x32_f16(aF[_fm][0], BR[_fn][0], acc[(MOFF)+_fm][(NOFF)+_fn], 0, 0, 0); \
    acc[(MOFF)+_fm][(NOFF)+_fn] = __builtin_amdgcn_mfma_f32_16x16x32_f16(aF[_fm][1], BR[_fn][1], acc[(MOFF)+_fm][(NOFF)+_fn], 0, 0, 0); \
  } \
  __builtin_amdgcn_s_setprio(0); \
} while (0)

__global__ __launch_bounds__(512, 2) void gemm8(const half_t* __restrict__ A, int lda,
                                                const half_t* __restrict__ Bt,
                                                const float* __restrict__ bias,
                                                half_t* __restrict__ C, int ldc,
                                                const int* skip) {
  if (skip && *skip == 0) return;
  extern __shared__ char smem[];
  const int t = threadIdx.x;
  const int ln = t & 63, wid = t >> 6;
  const int wm = wid >> 2, wn = wid & 3;

  const int gx = gridDim.x;
  const int nwg = gx * gridDim.y;
  const int orig = blockIdx.y * gx + blockIdx.x;
  const int swz = (orig & 7) * (nwg >> 3) + (orig >> 3);
  const int bx = swz % gx, by = swz / gx;
  const int n0 = bx * 256, m0 = by * 256;

  const int r8 = (t >> 3) & 7;
  const int grn = (t & 7) ^ r8;
  const int wbA = wid * 8;
  const int wbB = ((wid >> 2) << 6) + (wid & 3) * 8;
  const half_t* gA = A + (size_t)m0 * lda;
  const half_t* gB = Bt + (size_t)n0 * 1024;

  const int rA = (wm * 128 + (ln & 15)) * 128;
  const int rB = (wn * 64 + (ln & 15)) * 128;
  const int gsw0 = (((ln >> 4)) ^ (ln & 7)) << 4;
  const int gsw1 = ((4 | (ln >> 4)) ^ (ln & 7)) << 4;

  f32x4 acc[8][4] = {};
  f16x8 aF[4][2], bL[2][2], bH[2][2];

  // prologue: tile0 complete, tile1 Aα,Bγ,Aβ (Bδ(1) staged at i=0 P1)
  SA2(0, 0, 0); SB2(0, 0, 0); SA2(0, 64, 0); SB2(0, 32, 0);
  SA2(1, 0, 1); SB2(1, 0, 1); SA2(1, 64, 1);
  WAITV(6); BARRIER();

#pragma unroll 1
  for (int i = 0; i < 8; ++i) {
    const int kb = 2 * i + 1;
    const int kc = 2 * i + 2;
    const int kd = 2 * i + 3;
    const bool f = (i < 7);
    // ---- P1: read aLow+bL+bH (buf0); stage Bδ(b); Q0
    LOAD_A(0, 0); LOAD_B(bL, 0, 0); LOAD_B(bH, 0, 2);
    SB2(1, 32, kb);
    QUAD(bL, 0, 0); BARRIER();
    // ---- P2: stage Aα(c); Q1 (operands already in regs)
    if (f) SA2(0, 0, kc);
    QUAD(bH, 0, 2); BARRIER();
    // ---- P3: read aHigh(buf0); stage Bγ(c); Q2
    LOAD_A(0, 4);
    if (f) SB2(0, 0, kc);
    QUAD(bH, 4, 2); BARRIER();
    // ---- P4: stage Aβ(c); counted wait; Q3 (ready)
    if (f) { SA2(0, 64, kc); WAITV(6); } else WAITV(0);
    QUAD(bL, 4, 0); BARRIER();
    // ---- P5: reads (buf1); stage Bδ(c); Q0
    LOAD_A(1, 0); LOAD_B(bL, 1, 0); LOAD_B(bH, 1, 2);
    if (f) SB2(0, 32, kc);
    QUAD(bL, 0, 0); BARRIER();
    // ---- P6: stage Aα(d); Q1
    if (f) SA2(1, 0, kd);
    QUAD(bH, 0, 2); BARRIER();
    // ---- P7: read aHigh(buf1); stage Bγ(d); Q2
    LOAD_A(1, 4);
    if (f) SB2(1, 0, kd);
    QUAD(bH, 4, 2); BARRIER();
    // ---- P8: stage Aβ(d); counted wait; Q3
    if (f) { SA2(1, 64, kd); WAITV(6); }
    QUAD(bL, 4, 0); BARRIER();
  }

  const int r0 = m0 + wm * 128 + ((ln >> 4) << 2);
  const int c0 = n0 + wn * 64 + (ln & 15);
  float bb[4];
#pragma unroll
  for (int fn = 0; fn < 4; ++fn) bb[fn] = bias[c0 + fn * 16];
#pragma unroll
  for (int fm = 0; fm < 8; ++fm)
#pragma unroll
    for (int fn = 0; fn < 4; ++fn) {
      const int col = c0 + fn * 16;
      const int row = r0 + fm * 16;
#pragma unroll
      for (int r = 0; r < 4; ++r)
        C[(size_t)(row + r) * ldc + col] = (half_t)(acc[fm][fn][r] + bb[fn]);
    }
}

// ---------------- row softmax over D=1024, logits scaled 1/32 ----------------
__global__ __launch_bounds__(256) void softmax_k(const half_t* __restrict__ L,
                                                 half_t* __restrict__ O,
                                                 const int* skip) {
  if (skip && *skip == 0) return;
  const size_t row = blockIdx.x;
  const int t = threadIdx.x;
  f16x4 v = *(const f16x4*)(L + row * D_MODEL + t * 4);
  float x[4];
#pragma unroll
  for (int i = 0; i < 4; i++) x[i] = (float)v[i] * 0.03125f;
  float mx = fmaxf(fmaxf(x[0], x[1]), fmaxf(x[2], x[3]));
#pragma unroll
  for (int off = 32; off > 0; off >>= 1) mx = fmaxf(mx, __shfl_xor(mx, off, 64));
  __shared__ float sm[4], ssum[4];
  const int wv = t >> 6, ln = t & 63;
  if (ln == 0) sm[wv] = mx;
  __syncthreads();
  mx = fmaxf(fmaxf(sm[0], sm[1]), fmaxf(sm[2], sm[3]));
  float e[4]; float s = 0.f;
#pragma unroll
  for (int i = 0; i < 4; i++) { e[i] = expf(x[i] - mx); s += e[i]; }
#pragma unroll
  for (int off = 32; off > 0; off >>= 1) s += __shfl_xor(s, off, 64);
  if (ln == 0) ssum[wv] = s;
  __syncthreads();
  s = ssum[0] + ssum[1] + ssum[2] + ssum[3];
  const float r = 1.0f / s;
  f16x4 o;
#pragma unroll
  for (int i = 0; i < 4; i++) o[i] = (half_t)(e[i] * r);
  *(f16x4*)(O + row * D_MODEL + t * 4) = o;
}

// ---------------- cumsum pass 1 ----------------
__global__ __launch_bounds__(256) void cs_partial(const int* __restrict__ nz,
                                                  const float* __restrict__ wv,
                                                  const half_t* __restrict__ A, int ldA,
                                                  const half_t* __restrict__ B, int ldB,
                                                  float* __restrict__ part) {
  const int d = blockIdx.x * 256 + threadIdx.x;
  const int c = blockIdx.y;
  const int bb = blockIdx.z;
  const size_t s0 = (size_t)bb * SEQ + (size_t)c * SC;
  const half_t* pa = A + s0 * ldA + d;
  const half_t* pb = B + s0 * ldB + d;
  float acc = 0.f;
  if (*nz == 0) {
    const float w = wv[d];
#pragma unroll 8
    for (int s = 0; s < SC; s++) acc += w * (float)pb[(size_t)s * ldB];
  } else {
#pragma unroll 8
    for (int s = 0; s < SC; s++) acc += (float)pa[(size_t)s * ldA] * (float)pb[(size_t)s * ldB];
  }
  part[((size_t)bb * NC + c) * D_MODEL + d] = acc;
}

// ---------------- cumsum pass 1 for stage 2 (shortcut uses msum) ----------------
__global__ __launch_bounds__(256) void cs_partial2(const int* __restrict__ nz,
                                                   const float* __restrict__ wv,
                                                   const float* __restrict__ msum,
                                                   const half_t* __restrict__ A, int ldA,
                                                   const half_t* __restrict__ B, int ldB,
                                                   float* __restrict__ part) {
  const int d = blockIdx.x * 256 + threadIdx.x;
  const int c = blockIdx.y;
  const int bb = blockIdx.z;
  const size_t idx = ((size_t)bb * NC + c) * D_MODEL + d;
  if (*nz == 0) {
    part[idx] = wv[d] * msum[idx];
    return;
  }
  const size_t s0 = (size_t)bb * SEQ + (size_t)c * SC;
  const half_t* pa = A + s0 * ldA + d;
  const half_t* pb = B + s0 * ldB + d;
  float acc = 0.f;
#pragma unroll 8
  for (int s = 0; s < SC; s++) acc += (float)pa[(size_t)s * ldA] * (float)pb[(size_t)s * ldB];
  part[idx] = acc;
}

// ---------------- cumsum pass 2 ----------------
template <bool HALF_OUT>
__global__ __launch_bounds__(256) void cs_apply(const int* __restrict__ nz,
                                                const float* __restrict__ wv,
                                                const half_t* __restrict__ A, int ldA,
                                                const half_t* __restrict__ B, int ldB,
                                                const half_t* __restrict__ Cm, int ldC,
                                                const float* __restrict__ part,
                                                float* __restrict__ msum,
                                                half_t* __restrict__ OH,
                                                float* __restrict__ OF) {
  const int d = blockIdx.x * 256 + threadIdx.x;
  const int c = blockIdx.y;
  const int bb = blockIdx.z;
  float acc = 0.f;
  for (int cc = 0; cc < c; cc++) acc += part[((size_t)bb * NC + cc) * D_MODEL + d];
  const size_t s0 = (size_t)bb * SEQ + (size_t)c * SC;
  float ms = 0.f;
  if (*nz == 0) {
    const float w = wv[d];
#pragma unroll 4
    for (int s = 0; s < SC; s++) {
      const size_t sg = s0 + s;
      acc += w * (float)B[sg * ldB + d];
      const float pooled = acc / (float)(c * SC + s + 1);
      const float m = pooled * (float)Cm[sg * ldC + d];
      ms += m;
      if (HALF_OUT) OH[sg * D_MODEL + d] = (half_t)m;
      else          OF[sg * D_MODEL + d] = m;
    }
  } else {
#pragma unroll 4
    for (int s = 0; s < SC; s++) {
      const size_t sg = s0 + s;
      acc += (float)A[sg * ldA + d] * (float)B[sg * ldB + d];
      const float pooled = acc / (float)(c * SC + s + 1);
      const float m = pooled * (float)Cm[sg * ldC + d];
      ms += m;
      if (HALF_OUT) OH[sg * D_MODEL + d] = (half_t)m;
      else          OF[sg * D_MODEL + d] = m;
    }
  }
  if (msum) msum[((size_t)bb * NC + c) * D_MODEL + d] = ms;
}

extern "C" void kernel_launch(void* const* d_in, const int* in_sizes, int n_in,
                              void* d_out, int out_size, void* d_ws, size_t ws_size,
                              hipStream_t stream) {
  const float* x     = (const float*)d_in[0];
  const float* Wq    = (const float*)d_in[2];
  const float* bq    = (const float*)d_in[3];
  const float* Wqa   = (const float*)d_in[4];
  const float* bqa   = (const float*)d_in[5];
  const float* Wk    = (const float*)d_in[6];
  const float* bk    = (const float*)d_in[7];
  const float* Wka   = (const float*)d_in[8];
  const float* bka   = (const float*)d_in[9];
  const float* Wv    = (const float*)d_in[10];
  const float* bv    = (const float*)d_in[11];
  const float* gamma = (const float*)d_in[12];
  const float* beta  = (const float*)d_in[13];
  float* out = (float*)d_out;

  char* ws = (char*)d_ws;
  const size_t MB = 1024 * 1024;
  half_t* h16    = (half_t*)(ws + 0);         // 32MB: h, later reused as mixed16
  half_t* qkv16  = (half_t*)(ws + 32 * MB);   // 96MB: [16384][3072] q|k|v
  half_t* logits = (half_t*)(ws + 128 * MB);  // 32MB
  half_t* wcat   = (half_t*)(ws + 160 * MB);  // 6MB
  half_t* wqa16  = (half_t*)(ws + 166 * MB);  // 2MB
  half_t* wka16  = (half_t*)(ws + 168 * MB);  // 2MB
  float*  bcat   = (float*)(ws + 170 * MB);   // 12KB
  float*  part   = (float*)(ws + 170 * MB + 64 * 1024);   // 512KB
  float*  msum   = (float*)(ws + 170 * MB + 1024 * 1024); // 512KB
  float*  qwv    = (float*)(ws + 170 * MB + 1600 * 1024); // 4KB
  float*  kwv    = (float*)(ws + 170 * MB + 1604 * 1024); // 4KB
  int*    flags  = (int*)(ws + 170 * MB + 1608 * 1024);   // 8B

  half_t* q16 = qkv16;            // lda 3072
  half_t* k16 = qkv16 + 1024;
  half_t* v16 = qkv16 + 2048;
  half_t* mixed16 = h16;
  half_t* sw = logits;

  hipFuncSetAttribute((const void*)gemm8, hipFuncAttributeMaxDynamicSharedMemorySize, 131072);

  zero_flags<<<1, 64, 0, stream>>>(flags);
  detect_nz<<<512, 256, 0, stream>>>(Wqa, Wka, flags);
  bias_softmax<<<2, 256, 0, stream>>>(bqa, bka, qwv, kwv);
  prep_w<<<5120, 256, 0, stream>>>(Wq, Wk, Wv, Wqa, Wka, wcat, wqa16, wka16);
  copy_bias<<<12, 256, 0, stream>>>(bq, bk, bv, bcat);
  ln_kernel<<<ROWS, 256, 0, stream>>>(x, gamma, beta, h16);
  // q|k|v = h @ [Wq|Wk|Wv] + b   (M=16384, N=3072, K=1024)
  gemm8<<<dim3(12, 64), 512, 131072, stream>>>(h16, 1024, wcat, bcat, qkv16, 3072, nullptr);
  // logits = q @ Wqa + bqa  (skipped when Wqa == 0)
  gemm8<<<dim3(4, 64), 512, 131072, stream>>>(q16, 3072, wqa16, bqa, logits, 1024, flags);
  softmax_k<<<ROWS, 256, 0, stream>>>(logits, sw, flags);
  // mixed = (cumsum(qw.*q)/scale) .* k
  cs_partial<<<dim3(4, NC, BS), 256, 0, stream>>>(flags, qwv, sw, 1024, q16, 3072, part);
  cs_apply<true><<<dim3(4, NC, BS), 256, 0, stream>>>(flags, qwv, sw, 1024, q16, 3072,
                                                      k16, 3072, part, msum, mixed16, nullptr);
  // logits = mixed @ Wka + bka  (skipped when Wka == 0)
  gemm8<<<dim3(4, 64), 512, 131072, stream>>>(mixed16, 1024, wka16, bka, logits, 1024, flags + 1);
  softmax_k<<<ROWS, 256, 0, stream>>>(logits, sw, flags + 1);
  // out = (cumsum(kw.*mixed)/scale) .* v
  cs_partial2<<<dim3(4, NC, BS), 256, 0, stream>>>(flags + 1, kwv, msum, sw, 1024,
                                                   mixed16, 1024, part);
  cs_apply<false><<<dim3(4, NC, BS), 256, 0, stream>>>(flags + 1, kwv, sw, 1024, mixed16, 1024,
                                                       v16, 3072, part, nullptr, nullptr, out);
}